// Round 1
// baseline (486.817 us; speedup 1.0000x reference)
//
#include <hip/hip_runtime.h>

typedef _Float16 half8 __attribute__((ext_vector_type(8)));
typedef float floatx4 __attribute__((ext_vector_type(4)));

#define SEQ 2048
#define DMODEL 1024
#define NHEADS 16
#define HEADDIM 64
#define PW 5120   // proj row width: q|k|v|kg|vg

// ---------------- fp32 -> fp16 convert (x) ----------------
__global__ __launch_bounds__(256) void k_cvt_x(const float* __restrict__ x,
                                               _Float16* __restrict__ xh, int n) {
  int i = blockIdx.x * 256 + threadIdx.x;
  if (i < n) xh[i] = (_Float16)x[i];
}

// ---------------- weight transpose + convert: Wt[n][k] = (half)W[k][n] ----------------
__global__ __launch_bounds__(256) void k_transpose_w(
    const float* __restrict__ w0, const float* __restrict__ w1, const float* __restrict__ w2,
    const float* __restrict__ w3, const float* __restrict__ w4, const float* __restrict__ w5,
    _Float16* __restrict__ wcat, _Float16* __restrict__ wot) {
  __shared__ float tile[32][33];
  int z = blockIdx.z;
  const float* W = (z == 0) ? w0 : (z == 1) ? w1 : (z == 2) ? w2
                 : (z == 3) ? w3 : (z == 4) ? w4 : w5;
  _Float16* dst = (z < 5) ? (wcat + (size_t)z * 1024 * 1024) : wot;
  int k0 = blockIdx.x * 32, n0 = blockIdx.y * 32;
  int tx = threadIdx.x, ty = threadIdx.y;  // 32 x 8
  #pragma unroll
  for (int r = ty; r < 32; r += 8)
    tile[r][tx] = W[(size_t)(k0 + r) * DMODEL + n0 + tx];
  __syncthreads();
  #pragma unroll
  for (int r = ty; r < 32; r += 8)
    dst[(size_t)(n0 + r) * DMODEL + k0 + tx] = (_Float16)tile[tx][r];
}

// ---------------- fp16 MFMA GEMM: C[M,N] = A[M,K] @ Bt[N,K]^T ----------------
// 64x64 tile, BK=64, 4 waves (2x2 of 32x32), 16x16x32 MFMA.
// A-frag: A[m=lane&15][k=(lane>>4)*8+j]; B-frag: B[k=(lane>>4)*8+j][n=lane&15];
// D: row=(lane>>4)*4+reg, col=lane&15  (verified layouts, learn_hip m89/m91).
template <bool HALF_OUT>
__global__ __launch_bounds__(256) void k_gemm(const _Float16* __restrict__ A,
                                              const _Float16* __restrict__ Bt,
                                              void* __restrict__ Cv, int M, int N, int K) {
  __shared__ _Float16 As[64][72];  // +8 halfs pad: row stride 144B -> <=2-way conflicts (free)
  __shared__ _Float16 Bs[64][72];
  const int tid = threadIdx.x;
  const int lane = tid & 63;
  const int wave = tid >> 6;
  const int wm = (wave >> 1) * 32;
  const int wn = (wave & 1) * 32;
  const int row16 = lane & 15;
  const int q4 = lane >> 4;
  const int m0 = blockIdx.x * 64;
  const int n0 = blockIdx.y * 64;

  floatx4 acc[2][2];
  #pragma unroll
  for (int a = 0; a < 2; ++a)
    #pragma unroll
    for (int b = 0; b < 2; ++b) acc[a][b] = (floatx4){0.f, 0.f, 0.f, 0.f};

  for (int k0 = 0; k0 < K; k0 += 64) {
    __syncthreads();
    #pragma unroll
    for (int rep = 0; rep < 2; ++rep) {
      int c = tid + rep * 256;     // 512 chunks of 16B per tile
      int r = c >> 3, q = c & 7;
      *(half8*)&As[r][q * 8] = *(const half8*)(A + (size_t)(m0 + r) * K + k0 + q * 8);
      *(half8*)&Bs[r][q * 8] = *(const half8*)(Bt + (size_t)(n0 + r) * K + k0 + q * 8);
    }
    __syncthreads();
    #pragma unroll
    for (int kk = 0; kk < 64; kk += 32) {
      half8 a0 = *(const half8*)&As[wm + row16][kk + q4 * 8];
      half8 a1 = *(const half8*)&As[wm + 16 + row16][kk + q4 * 8];
      half8 b0 = *(const half8*)&Bs[wn + row16][kk + q4 * 8];
      half8 b1 = *(const half8*)&Bs[wn + 16 + row16][kk + q4 * 8];
      acc[0][0] = __builtin_amdgcn_mfma_f32_16x16x32_f16(a0, b0, acc[0][0], 0, 0, 0);
      acc[0][1] = __builtin_amdgcn_mfma_f32_16x16x32_f16(a0, b1, acc[0][1], 0, 0, 0);
      acc[1][0] = __builtin_amdgcn_mfma_f32_16x16x32_f16(a1, b0, acc[1][0], 0, 0, 0);
      acc[1][1] = __builtin_amdgcn_mfma_f32_16x16x32_f16(a1, b1, acc[1][1], 0, 0, 0);
    }
  }
  #pragma unroll
  for (int im = 0; im < 2; ++im)
    #pragma unroll
    for (int in = 0; in < 2; ++in)
      #pragma unroll
      for (int r = 0; r < 4; ++r) {
        int row = m0 + wm + im * 16 + q4 * 4 + r;
        int col = n0 + wn + in * 16 + row16;
        if (HALF_OUT)
          ((_Float16*)Cv)[(size_t)row * N + col] = (_Float16)acc[im][in][r];
        else
          ((float*)Cv)[(size_t)row * N + col] = acc[im][in][r];
      }
}

// ---------------- RoPE on q (cols 0..1023) and k (cols 1024..2047), in place ----------------
__global__ __launch_bounds__(256) void k_rope(_Float16* __restrict__ proj,
                                              const float* __restrict__ cos_t,
                                              const float* __restrict__ sin_t,
                                              const int* __restrict__ pos) {
  int tid = blockIdx.x * 256 + threadIdx.x;  // SEQ*NHEADS*32 = 1,048,576
  int s = tid >> 9;
  int rem = tid & 511;
  int h = rem >> 5;
  int d = rem & 31;
  int p = pos[s];
  float c1 = cos_t[p * 64 + d], s1 = sin_t[p * 64 + d];
  float c2 = cos_t[p * 64 + d + 32], s2 = sin_t[p * 64 + d + 32];
  size_t base = (size_t)s * PW + h * 64 + d;
  #pragma unroll
  for (int off = 0; off < 2048; off += 1024) {  // q then k
    float a = (float)proj[base + off];
    float b = (float)proj[base + off + 32];
    proj[base + off]      = (_Float16)(a * c1 - b * s1);
    proj[base + off + 32] = (_Float16)(b * c2 + a * s2);
  }
}

// ---------------- attention: one wave per (row i, head h) ----------------
__device__ __forceinline__ float wave_sum(float v) {
  #pragma unroll
  for (int off = 32; off; off >>= 1) v += __shfl_xor(v, off, 64);
  return v;
}
__device__ __forceinline__ float wave_max(float v) {
  #pragma unroll
  for (int off = 32; off; off >>= 1) v = fmaxf(v, __shfl_xor(v, off, 64));
  return v;
}

__global__ __launch_bounds__(64) void k_attn(const _Float16* __restrict__ proj,
                                             _Float16* __restrict__ out) {
  const int i = blockIdx.x;
  const int h = blockIdx.y;
  const int lane = threadIdx.x;
  const float scale = 0.125f;  // 1/sqrt(64)
  __shared__ float q_s[64];
  __shared__ float p_s[260];

  const int hb = h * 64;
  float qv = (float)proj[(size_t)i * PW + hb + lane];
  q_s[lane] = qv;
  __syncthreads();

  // ---- global attention: 4 columns of kg/vg, no causal mask ----
  float sg[4];
  #pragma unroll
  for (int g = 0; g < 4; ++g) {
    float kgv = (float)proj[(size_t)g * PW + 3072 + hb + lane];
    sg[g] = wave_sum(qv * kgv) * scale;
  }
  float mg = fmaxf(fmaxf(sg[0], sg[1]), fmaxf(sg[2], sg[3]));
  float dg = 0.f, og = 0.f;
  #pragma unroll
  for (int g = 0; g < 4; ++g) {
    float p = __expf(sg[g] - mg);
    dg += p;
    og += p * (float)proj[(size_t)g * PW + 4096 + hb + lane];
  }
  og /= dg;

  // ---- local sliding-window attention ----
  float ol;
  if (i < 260) {
    // Some global col is in-window: its fp32 score is exactly 1e9 (raw absorbed),
    // so softmax = uniform average over in-window global cols. (fp32 ref semantics.)
    int jmin = (i >= 256) ? (i - 256) : 0;
    int jmax = (i < 3) ? i : 3;
    float acc = 0.f;
    for (int j = jmin; j <= jmax; ++j)
      acc += (float)proj[(size_t)j * PW + 2048 + hb + lane];
    ol = acc / (float)(jmax - jmin + 1);
  } else {
    const int jlo = i - 256;  // window [jlo, i], 257 cols; global cols 0..3 score exactly 0
    float qreg[64];
    #pragma unroll
    for (int d = 0; d < 64; ++d) qreg[d] = q_s[d];

    const _Float16* kbase = proj + 1024 + hb;
    float sc[5];
    float smax = -1e30f;
    #pragma unroll
    for (int c = 0; c < 5; ++c) {
      int jj = c * 64 + lane;
      float s = -1e30f;
      if (jj <= 256) {
        const _Float16* kp = kbase + (size_t)(jlo + jj) * PW;
        float acc = 0.f;
        #pragma unroll
        for (int d8 = 0; d8 < 8; ++d8) {
          half8 kv = *(const half8*)(kp + d8 * 8);
          #pragma unroll
          for (int t = 0; t < 8; ++t) acc += qreg[d8 * 8 + t] * (float)kv[t];
        }
        s = acc * scale;
      }
      sc[c] = s;
      smax = fmaxf(smax, s);
    }
    float m = wave_max(smax);
    m = fmaxf(m, 0.f);  // 4 global columns contribute score exactly 0
    float dloc = 0.f;
    #pragma unroll
    for (int c = 0; c < 5; ++c) {
      int jj = c * 64 + lane;
      if (jj <= 256) {
        float p = __expf(sc[c] - m);
        p_s[jj] = p;
        dloc += p;
      }
    }
    float den = wave_sum(dloc);
    float e0 = __expf(-m);
    den += 4.f * e0;
    __syncthreads();
    const _Float16* vbase = proj + 2048 + hb + lane;
    float acc = 0.f;
    #pragma unroll 4
    for (int jj = 0; jj <= 256; ++jj)
      acc += p_s[jj] * (float)vbase[(size_t)(jlo + jj) * PW];
    #pragma unroll
    for (int g = 0; g < 4; ++g) acc += e0 * (float)vbase[(size_t)g * PW];
    ol = acc / den;
  }

  out[(size_t)i * DMODEL + hb + lane] = (_Float16)(ol + og);
}

// ---------------- launcher ----------------
extern "C" void kernel_launch(void* const* d_in, const int* in_sizes, int n_in,
                              void* d_out, int out_size, void* d_ws, size_t ws_size,
                              hipStream_t stream) {
  const float* x     = (const float*)d_in[0];
  const float* cos_t = (const float*)d_in[1];
  const float* sin_t = (const float*)d_in[2];
  const int*   pos   = (const int*)d_in[3];
  const float* Wqs   = (const float*)d_in[4];
  const float* Wks   = (const float*)d_in[5];
  const float* Wvs   = (const float*)d_in[6];
  // d_in[7] = Wqg (unused by the reference forward math)
  const float* Wkg   = (const float*)d_in[8];
  const float* Wvg   = (const float*)d_in[9];
  const float* Wo    = (const float*)d_in[10];
  float* out = (float*)d_out;

  char* ws = (char*)d_ws;
  _Float16* xh   = (_Float16*)(ws);                        //  4 MB [2048][1024]
  _Float16* wcat = (_Float16*)(ws + (4u << 20));           // 10 MB [5120][1024] (W^T x5)
  _Float16* wot  = (_Float16*)(ws + (14u << 20));          //  2 MB [1024][1024] Wo^T
  _Float16* proj = (_Float16*)(ws + (16u << 20));          // 20 MB [2048][5120]
  _Float16* attn = (_Float16*)(ws + (36u << 20));          //  4 MB [2048][1024]

  k_cvt_x<<<(SEQ * DMODEL + 255) / 256, 256, 0, stream>>>(x, xh, SEQ * DMODEL);
  k_transpose_w<<<dim3(32, 32, 6), dim3(32, 8), 0, stream>>>(Wqs, Wks, Wvs, Wkg, Wvg, Wo,
                                                             wcat, wot);
  // proj[s][0:1024]=q, [1024:2048]=k, [2048:3072]=v, [3072:4096]=kg, [4096:5120]=vg
  k_gemm<true><<<dim3(SEQ / 64, PW / 64), 256, 0, stream>>>(xh, wcat, proj, SEQ, PW, DMODEL);
  k_rope<<<(SEQ * NHEADS * 32) / 256, 256, 0, stream>>>(proj, cos_t, sin_t, pos);
  k_attn<<<dim3(SEQ, NHEADS), 64, 0, stream>>>(proj, attn);
  k_gemm<false><<<dim3(SEQ / 64, DMODEL / 64), 256, 0, stream>>>(attn, wot, out, SEQ, DMODEL,
                                                                 DMODEL);
}

// Round 2
// 206.211 us; speedup vs baseline: 2.3608x; 2.3608x over previous
//
#include <hip/hip_runtime.h>

typedef _Float16 half8 __attribute__((ext_vector_type(8)));
typedef float floatx4 __attribute__((ext_vector_type(4)));

#define SEQ 2048
#define DMODEL 1024
#define NHEADS 16
#define HEADDIM 64
#define PW 5120   // proj row width: q|k|v|kg|vg

// ---------------- fp32 -> fp16 convert (x) ----------------
__global__ __launch_bounds__(256) void k_cvt_x(const float* __restrict__ x,
                                               _Float16* __restrict__ xh, int n) {
  int i = blockIdx.x * 256 + threadIdx.x;
  if (i < n) xh[i] = (_Float16)x[i];
}

// ---------------- weight transpose + convert: Wt[n][k] = (half)W[k][n] ----------------
__global__ __launch_bounds__(256) void k_transpose_w(
    const float* __restrict__ w0, const float* __restrict__ w1, const float* __restrict__ w2,
    const float* __restrict__ w3, const float* __restrict__ w4, const float* __restrict__ w5,
    _Float16* __restrict__ wcat, _Float16* __restrict__ wot) {
  __shared__ float tile[32][33];
  int z = blockIdx.z;
  const float* W = (z == 0) ? w0 : (z == 1) ? w1 : (z == 2) ? w2
                 : (z == 3) ? w3 : (z == 4) ? w4 : w5;
  _Float16* dst = (z < 5) ? (wcat + (size_t)z * 1024 * 1024) : wot;
  int k0 = blockIdx.x * 32, n0 = blockIdx.y * 32;
  int tx = threadIdx.x, ty = threadIdx.y;  // 32 x 8
  #pragma unroll
  for (int r = ty; r < 32; r += 8)
    tile[r][tx] = W[(size_t)(k0 + r) * DMODEL + n0 + tx];
  __syncthreads();
  #pragma unroll
  for (int r = ty; r < 32; r += 8)
    dst[(size_t)(n0 + r) * DMODEL + k0 + tx] = (_Float16)tile[tx][r];
}

// ---------------- fp16 MFMA GEMM: C[M,N] = A[M,K] @ Bt[N,K]^T ----------------
template <bool HALF_OUT>
__global__ __launch_bounds__(256) void k_gemm(const _Float16* __restrict__ A,
                                              const _Float16* __restrict__ Bt,
                                              void* __restrict__ Cv, int M, int N, int K) {
  __shared__ _Float16 As[64][72];
  __shared__ _Float16 Bs[64][72];
  const int tid = threadIdx.x;
  const int lane = tid & 63;
  const int wave = tid >> 6;
  const int wm = (wave >> 1) * 32;
  const int wn = (wave & 1) * 32;
  const int row16 = lane & 15;
  const int q4 = lane >> 4;
  const int m0 = blockIdx.x * 64;
  const int n0 = blockIdx.y * 64;

  floatx4 acc[2][2];
  #pragma unroll
  for (int a = 0; a < 2; ++a)
    #pragma unroll
    for (int b = 0; b < 2; ++b) acc[a][b] = (floatx4){0.f, 0.f, 0.f, 0.f};

  for (int k0 = 0; k0 < K; k0 += 64) {
    __syncthreads();
    #pragma unroll
    for (int rep = 0; rep < 2; ++rep) {
      int c = tid + rep * 256;
      int r = c >> 3, q = c & 7;
      *(half8*)&As[r][q * 8] = *(const half8*)(A + (size_t)(m0 + r) * K + k0 + q * 8);
      *(half8*)&Bs[r][q * 8] = *(const half8*)(Bt + (size_t)(n0 + r) * K + k0 + q * 8);
    }
    __syncthreads();
    #pragma unroll
    for (int kk = 0; kk < 64; kk += 32) {
      half8 a0 = *(const half8*)&As[wm + row16][kk + q4 * 8];
      half8 a1 = *(const half8*)&As[wm + 16 + row16][kk + q4 * 8];
      half8 b0 = *(const half8*)&Bs[wn + row16][kk + q4 * 8];
      half8 b1 = *(const half8*)&Bs[wn + 16 + row16][kk + q4 * 8];
      acc[0][0] = __builtin_amdgcn_mfma_f32_16x16x32_f16(a0, b0, acc[0][0], 0, 0, 0);
      acc[0][1] = __builtin_amdgcn_mfma_f32_16x16x32_f16(a0, b1, acc[0][1], 0, 0, 0);
      acc[1][0] = __builtin_amdgcn_mfma_f32_16x16x32_f16(a1, b0, acc[1][0], 0, 0, 0);
      acc[1][1] = __builtin_amdgcn_mfma_f32_16x16x32_f16(a1, b1, acc[1][1], 0, 0, 0);
    }
  }
  #pragma unroll
  for (int im = 0; im < 2; ++im)
    #pragma unroll
    for (int in = 0; in < 2; ++in)
      #pragma unroll
      for (int r = 0; r < 4; ++r) {
        int row = m0 + wm + im * 16 + q4 * 4 + r;
        int col = n0 + wn + in * 16 + row16;
        if (HALF_OUT)
          ((_Float16*)Cv)[(size_t)row * N + col] = (_Float16)acc[im][in][r];
        else
          ((float*)Cv)[(size_t)row * N + col] = acc[im][in][r];
      }
}

// ---------------- RoPE on q and k, in place ----------------
__global__ __launch_bounds__(256) void k_rope(_Float16* __restrict__ proj,
                                              const float* __restrict__ cos_t,
                                              const float* __restrict__ sin_t,
                                              const int* __restrict__ pos) {
  int tid = blockIdx.x * 256 + threadIdx.x;
  int s = tid >> 9;
  int rem = tid & 511;
  int h = rem >> 5;
  int d = rem & 31;
  int p = pos[s];
  float c1 = cos_t[p * 64 + d], s1 = sin_t[p * 64 + d];
  float c2 = cos_t[p * 64 + d + 32], s2 = sin_t[p * 64 + d + 32];
  size_t base = (size_t)s * PW + h * 64 + d;
  #pragma unroll
  for (int off = 0; off < 2048; off += 1024) {
    float a = (float)proj[base + off];
    float b = (float)proj[base + off + 32];
    proj[base + off]      = (_Float16)(a * c1 - b * s1);
    proj[base + off + 32] = (_Float16)(b * c2 + a * s2);
  }
}

// ---------------- MFMA flash attention: tiles 4..31 (rows 256..2047) ----------------
// One block per (64-row tile, head). 5 chunks of 64 cols over the 320-col window.
// Online softmax init m=0, l=4 encodes the 4 global cols whose fp32 score is exactly 0.
__global__ __launch_bounds__(256, 4) void k_attn_main(const _Float16* __restrict__ proj,
                                                      _Float16* __restrict__ out) {
  const int i0 = (blockIdx.x + 4) * 64;
  const int jlo = i0 - 256;
  const int hb = blockIdx.y * 64;
  const int tid = threadIdx.x;
  const int lane = tid & 63;
  const int w = tid >> 6;
  const int l15 = lane & 15;
  const int q4 = lane >> 4;

  __shared__ _Float16 Qs[64][72];
  __shared__ _Float16 Kc[64][72];
  __shared__ _Float16 Vtc[64][72];
  __shared__ _Float16 Ps[64][72];
  __shared__ _Float16 kg_s[4][64];
  __shared__ _Float16 vg_s[4][64];
  __shared__ float svg_s[64];
  __shared__ float pg_s[4][64];

  // ---- stage Q tile + global k/v vectors ----
  #pragma unroll
  for (int rep = 0; rep < 2; ++rep) {
    int c = tid + rep * 256;
    int r = c >> 3, q = c & 7;
    *(half8*)&Qs[r][q * 8] = *(const half8*)(proj + (size_t)(i0 + r) * PW + hb + q * 8);
  }
  {
    int g = tid >> 6, c2 = tid & 63;
    kg_s[g][c2] = proj[(size_t)g * PW + 3072 + hb + c2];
    vg_s[g][c2] = proj[(size_t)g * PW + 4096 + hb + c2];
    if (tid < 64) {
      float s = 0.f;
      #pragma unroll
      for (int g2 = 0; g2 < 4; ++g2) s += (float)proj[(size_t)g2 * PW + 2048 + hb + tid];
      svg_s[tid] = s;
    }
  }
  __syncthreads();

  // ---- global-attention probabilities for this tile's 64 rows -> pg_s ----
  {
    int rid = lane >> 2, part = lane & 3;
    int ro = w * 16 + rid;
    float sg[4];
    #pragma unroll
    for (int g = 0; g < 4; ++g) {
      float acc = 0.f;
      #pragma unroll
      for (int u = 0; u < 16; ++u)
        acc += (float)Qs[ro][part * 16 + u] * (float)kg_s[g][part * 16 + u];
      acc += __shfl_xor(acc, 1, 64);
      acc += __shfl_xor(acc, 2, 64);
      sg[g] = acc * 0.125f;
    }
    float mg = fmaxf(fmaxf(sg[0], sg[1]), fmaxf(sg[2], sg[3]));
    float dg = 0.f;
    #pragma unroll
    for (int g = 0; g < 4; ++g) dg += __expf(sg[g] - mg);
    pg_s[part][ro] = __expf(sg[part] - mg) / dg;
  }

  // hoisted Q A-frags (wave w covers rows w*16..w*16+15)
  half8 qf0 = *(const half8*)&Qs[w * 16 + l15][q4 * 8];
  half8 qf1 = *(const half8*)&Qs[w * 16 + l15][32 + q4 * 8];

  float m_r[4] = {0.f, 0.f, 0.f, 0.f};
  float l_r[4] = {4.f, 4.f, 4.f, 4.f};  // 4 global cols with score exactly 0
  floatx4 oacc[4];
  #pragma unroll
  for (int cb = 0; cb < 4; ++cb) oacc[cb] = (floatx4){0.f, 0.f, 0.f, 0.f};

  for (int cc = 0; cc < 5; ++cc) {
    const int jbase = jlo + cc * 64;
    __syncthreads();  // prior iter's K/Vt/Ps reads done before restage
    // stage K chunk (row-major) and V chunk (transposed)
    #pragma unroll
    for (int rep = 0; rep < 2; ++rep) {
      int c = tid + rep * 256;
      int r = c >> 3, q = c & 7;
      *(half8*)&Kc[r][q * 8] =
          *(const half8*)(proj + (size_t)(jbase + r) * PW + 1024 + hb + q * 8);
    }
    #pragma unroll
    for (int it = 0; it < 16; ++it) {
      int e = tid + it * 256;
      int d = e & 63, j = e >> 6;
      Vtc[d][j] = proj[(size_t)(jbase + j) * PW + 2048 + hb + d];
    }
    __syncthreads();

    // QK^T for this chunk: 4 col-blocks of 16
    float sc[4][4];
    #pragma unroll
    for (int cb = 0; cb < 4; ++cb) {
      half8 b0 = *(const half8*)&Kc[cb * 16 + l15][q4 * 8];
      half8 b1 = *(const half8*)&Kc[cb * 16 + l15][32 + q4 * 8];
      floatx4 a = (floatx4){0.f, 0.f, 0.f, 0.f};
      a = __builtin_amdgcn_mfma_f32_16x16x32_f16(qf0, b0, a, 0, 0, 0);
      a = __builtin_amdgcn_mfma_f32_16x16x32_f16(qf1, b1, a, 0, 0, 0);
      #pragma unroll
      for (int r = 0; r < 4; ++r) sc[cb][r] = a[r];
    }

    // mask + online softmax update (per output row r of this lane)
    #pragma unroll
    for (int r = 0; r < 4; ++r) {
      int ri = w * 16 + q4 * 4 + r;
      float rowmax = -1e30f;
      #pragma unroll
      for (int cb = 0; cb < 4; ++cb) {
        int jjg = cc * 64 + cb * 16 + l15;
        bool valid = (jjg >= ri) && (jjg <= ri + 256);
        float s = valid ? sc[cb][r] * 0.125f : -1e30f;
        sc[cb][r] = s;
        rowmax = fmaxf(rowmax, s);
      }
      #pragma unroll
      for (int off = 1; off < 16; off <<= 1)
        rowmax = fmaxf(rowmax, __shfl_xor(rowmax, off, 64));
      float m_new = fmaxf(m_r[r], rowmax);
      float alpha = __expf(m_r[r] - m_new);
      float rs = 0.f;
      #pragma unroll
      for (int cb = 0; cb < 4; ++cb) {
        float p = __expf(sc[cb][r] - m_new);  // masked (-1e30) underflows to 0
        Ps[w * 16 + q4 * 4 + r][cb * 16 + l15] = (_Float16)p;
        rs += p;
      }
      #pragma unroll
      for (int off = 1; off < 16; off <<= 1) rs += __shfl_xor(rs, off, 64);
      l_r[r] = l_r[r] * alpha + rs;
      m_r[r] = m_new;
      #pragma unroll
      for (int cb = 0; cb < 4; ++cb) oacc[cb][r] *= alpha;
    }

    // PV: wave reads only its OWN 16 Ps rows (same-wave write->read, no barrier needed)
    half8 pf0 = *(const half8*)&Ps[w * 16 + l15][q4 * 8];
    half8 pf1 = *(const half8*)&Ps[w * 16 + l15][32 + q4 * 8];
    #pragma unroll
    for (int cb = 0; cb < 4; ++cb) {
      half8 v0 = *(const half8*)&Vtc[cb * 16 + l15][q4 * 8];
      half8 v1 = *(const half8*)&Vtc[cb * 16 + l15][32 + q4 * 8];
      oacc[cb] = __builtin_amdgcn_mfma_f32_16x16x32_f16(pf0, v0, oacc[cb], 0, 0, 0);
      oacc[cb] = __builtin_amdgcn_mfma_f32_16x16x32_f16(pf1, v1, oacc[cb], 0, 0, 0);
    }
  }

  // ---- epilogue: local (incl. zero-score global cols) + global attention ----
  #pragma unroll
  for (int r = 0; r < 4; ++r) {
    int ri = w * 16 + q4 * 4 + r;
    float e0 = __expf(-m_r[r]);
    float inv = 1.f / l_r[r];
    #pragma unroll
    for (int cb = 0; cb < 4; ++cb) {
      int col = cb * 16 + l15;
      float ol = (oacc[cb][r] + e0 * svg_s[col]) * inv;
      float og = 0.f;
      #pragma unroll
      for (int g = 0; g < 4; ++g) og += pg_s[g][ri] * (float)vg_s[g][col];
      out[(size_t)(i0 + ri) * DMODEL + hb + col] = (_Float16)(ol + og);
    }
  }
}

// ---------------- early rows (i < 260): absorbed-1e9 uniform average + global ----------------
__device__ __forceinline__ float wave_sum(float v) {
  #pragma unroll
  for (int off = 32; off; off >>= 1) v += __shfl_xor(v, off, 64);
  return v;
}

__global__ __launch_bounds__(64) void k_attn_early(const _Float16* __restrict__ proj,
                                                   _Float16* __restrict__ out) {
  const int i = blockIdx.x;
  const int h = blockIdx.y;
  const int lane = threadIdx.x;
  const float scale = 0.125f;
  const int hb = h * 64;
  float qv = (float)proj[(size_t)i * PW + hb + lane];

  // global attention
  float sg[4];
  #pragma unroll
  for (int g = 0; g < 4; ++g) {
    float kgv = (float)proj[(size_t)g * PW + 3072 + hb + lane];
    sg[g] = wave_sum(qv * kgv) * scale;
  }
  float mg = fmaxf(fmaxf(sg[0], sg[1]), fmaxf(sg[2], sg[3]));
  float dg = 0.f, og = 0.f;
  #pragma unroll
  for (int g = 0; g < 4; ++g) {
    float p = __expf(sg[g] - mg);
    dg += p;
    og += p * (float)proj[(size_t)g * PW + 4096 + hb + lane];
  }
  og /= dg;

  // local: in-window global col scores are exactly 1e9 -> uniform average
  int jmin = (i >= 256) ? (i - 256) : 0;
  int jmax = (i < 3) ? i : 3;
  float acc = 0.f;
  for (int j = jmin; j <= jmax; ++j)
    acc += (float)proj[(size_t)j * PW + 2048 + hb + lane];
  float ol = acc / (float)(jmax - jmin + 1);

  out[(size_t)i * DMODEL + hb + lane] = (_Float16)(ol + og);
}

// ---------------- launcher ----------------
extern "C" void kernel_launch(void* const* d_in, const int* in_sizes, int n_in,
                              void* d_out, int out_size, void* d_ws, size_t ws_size,
                              hipStream_t stream) {
  const float* x     = (const float*)d_in[0];
  const float* cos_t = (const float*)d_in[1];
  const float* sin_t = (const float*)d_in[2];
  const int*   pos   = (const int*)d_in[3];
  const float* Wqs   = (const float*)d_in[4];
  const float* Wks   = (const float*)d_in[5];
  const float* Wvs   = (const float*)d_in[6];
  const float* Wkg   = (const float*)d_in[8];
  const float* Wvg   = (const float*)d_in[9];
  const float* Wo    = (const float*)d_in[10];
  float* out = (float*)d_out;

  char* ws = (char*)d_ws;
  _Float16* xh   = (_Float16*)(ws);                        //  4 MB
  _Float16* wcat = (_Float16*)(ws + (4u << 20));           // 10 MB
  _Float16* wot  = (_Float16*)(ws + (14u << 20));          //  2 MB
  _Float16* proj = (_Float16*)(ws + (16u << 20));          // 20 MB
  _Float16* attn = (_Float16*)(ws + (36u << 20));          //  4 MB

  k_cvt_x<<<(SEQ * DMODEL + 255) / 256, 256, 0, stream>>>(x, xh, SEQ * DMODEL);
  k_transpose_w<<<dim3(32, 32, 6), dim3(32, 8), 0, stream>>>(Wqs, Wks, Wvs, Wkg, Wvg, Wo,
                                                             wcat, wot);
  k_gemm<true><<<dim3(SEQ / 64, PW / 64), 256, 0, stream>>>(xh, wcat, proj, SEQ, PW, DMODEL);
  k_rope<<<(SEQ * NHEADS * 32) / 256, 256, 0, stream>>>(proj, cos_t, sin_t, pos);
  k_attn_main<<<dim3(28, NHEADS), 256, 0, stream>>>(proj, attn);
  k_attn_early<<<dim3(260, NHEADS), 64, 0, stream>>>(proj, attn);  // overwrites rows 256..259
  k_gemm<false><<<dim3(SEQ / 64, DMODEL / 64), 256, 0, stream>>>(attn, wot, out, SEQ, DMODEL,
                                                                 DMODEL);
}

// Round 3
// 196.194 us; speedup vs baseline: 2.4813x; 1.0511x over previous
//
#include <hip/hip_runtime.h>

typedef _Float16 half8 __attribute__((ext_vector_type(8)));
typedef float floatx4 __attribute__((ext_vector_type(4)));

#define SEQ 2048
#define DMODEL 1024
#define NHEADS 16
#define HEADDIM 64
#define PW 5120   // proj row width: q|k|v|kg|vg

// ---------------- fp32 -> fp16 convert (x) ----------------
__global__ __launch_bounds__(256) void k_cvt_x(const float* __restrict__ x,
                                               _Float16* __restrict__ xh, int n) {
  int i = blockIdx.x * 256 + threadIdx.x;
  if (i < n) xh[i] = (_Float16)x[i];
}

// ---------------- weight transpose + convert: Wt[n][k] = (half)W[k][n] ----------------
__global__ __launch_bounds__(256) void k_transpose_w(
    const float* __restrict__ w0, const float* __restrict__ w1, const float* __restrict__ w2,
    const float* __restrict__ w3, const float* __restrict__ w4, const float* __restrict__ w5,
    _Float16* __restrict__ wcat, _Float16* __restrict__ wot) {
  __shared__ float tile[32][33];
  int z = blockIdx.z;
  const float* W = (z == 0) ? w0 : (z == 1) ? w1 : (z == 2) ? w2
                 : (z == 3) ? w3 : (z == 4) ? w4 : w5;
  _Float16* dst = (z < 5) ? (wcat + (size_t)z * 1024 * 1024) : wot;
  int k0 = blockIdx.x * 32, n0 = blockIdx.y * 32;
  int tx = threadIdx.x, ty = threadIdx.y;  // 32 x 8
  #pragma unroll
  for (int r = ty; r < 32; r += 8)
    tile[r][tx] = W[(size_t)(k0 + r) * DMODEL + n0 + tx];
  __syncthreads();
  #pragma unroll
  for (int r = ty; r < 32; r += 8)
    dst[(size_t)(n0 + r) * DMODEL + k0 + tx] = (_Float16)tile[tx][r];
}

// ---------------- m97-style 128x128 MFMA GEMM, global_load_lds + XOR swizzle ----------------
// C[M,N] = A[M,K] @ Bt[N,K]^T. 4 waves in 2x2 of 64x64; each wave 4x4 MFMA 16x16x32 tiles.
// LDS [128][64] halfs, 16B chunk at [row][cc] holds global k-chunk (cc ^ (row&7)) — the
// swizzle is applied on the GLOBAL source address (global_load_lds LDS dest is
// wave-uniform base + lane*16, m104/m108), making frag reads 2-way-max on banks (free).
// FUSE_ROPE: for n0 < 2048 (q|k regions), apply RoPE on fp32 acc in the epilogue;
// pair d <-> d+32 is acc[tm][tn] <-> acc[tm][tn^2] in the SAME lane.
template <bool HALF_OUT, bool FUSE_ROPE>
__global__ __launch_bounds__(256) void k_gemm128(const _Float16* __restrict__ A,
                                                 const _Float16* __restrict__ Bt,
                                                 void* __restrict__ Cv,
                                                 const float* __restrict__ cos_t,
                                                 const float* __restrict__ sin_t,
                                                 const int* __restrict__ pos,
                                                 int M, int N, int K) {
  __shared__ _Float16 As[128][64];
  __shared__ _Float16 Bs[128][64];
  const int tid = threadIdx.x;
  const int lane = tid & 63;
  const int w = tid >> 6;
  const int wm = (w >> 1) * 64;
  const int wn = (w & 1) * 64;
  const int l15 = lane & 15;
  const int q4 = lane >> 4;
  const int m0 = blockIdx.x * 128;
  const int n0 = blockIdx.y * 128;

  floatx4 acc[4][4];
  #pragma unroll
  for (int i = 0; i < 4; ++i)
    #pragma unroll
    for (int j = 0; j < 4; ++j) acc[i][j] = (floatx4){0.f, 0.f, 0.f, 0.f};

  _Float16* asBase = &As[0][0];
  _Float16* bsBase = &Bs[0][0];
  const int swz = l15 & 7;  // read-side swizzle key (row&7 == l15&7 for 16-aligned tiles)

  for (int k0 = 0; k0 < K; k0 += 64) {
    __syncthreads();  // prior-iter frag reads done before DMA overwrites
    #pragma unroll
    for (int it = 0; it < 4; ++it) {
      int c = it * 256 + tid;           // chunk id 0..1023 (16B each)
      int r = c >> 3, cc = c & 7;
      int g = cc ^ (r & 7);             // swizzled global k-chunk
      __builtin_amdgcn_global_load_lds(
          (const __attribute__((address_space(1))) void*)(A + (size_t)(m0 + r) * K + k0 + g * 8),
          (__attribute__((address_space(3))) void*)(asBase + (it * 256 + w * 64) * 8),
          16, 0, 0);
      __builtin_amdgcn_global_load_lds(
          (const __attribute__((address_space(1))) void*)(Bt + (size_t)(n0 + r) * K + k0 + g * 8),
          (__attribute__((address_space(3))) void*)(bsBase + (it * 256 + w * 64) * 8),
          16, 0, 0);
    }
    __syncthreads();  // compiler drains vmcnt(0) here

    #pragma unroll
    for (int kk = 0; kk < 2; ++kk) {
      int q = kk * 4 + q4;  // global k-chunk this quarter-wave needs
      half8 af[4], bf[4];
      #pragma unroll
      for (int t = 0; t < 4; ++t) {
        int ar = wm + t * 16 + l15;
        af[t] = *(const half8*)(asBase + (size_t)ar * 64 + ((q ^ swz) * 8));
        int br = wn + t * 16 + l15;
        bf[t] = *(const half8*)(bsBase + (size_t)br * 64 + ((q ^ swz) * 8));
      }
      #pragma unroll
      for (int i = 0; i < 4; ++i)
        #pragma unroll
        for (int j = 0; j < 4; ++j)
          acc[i][j] = __builtin_amdgcn_mfma_f32_16x16x32_f16(af[i], bf[j], acc[i][j], 0, 0, 0);
    }
  }

  // ---- epilogue ----
  #pragma unroll
  for (int tm = 0; tm < 4; ++tm) {
    #pragma unroll
    for (int r = 0; r < 4; ++r) {
      int row = m0 + wm + tm * 16 + q4 * 4 + r;
      float v[4];
      #pragma unroll
      for (int tn = 0; tn < 4; ++tn) v[tn] = acc[tm][tn][r];
      if (FUSE_ROPE && n0 < 2048) {
        int p = pos[row];
        #pragma unroll
        for (int tn = 0; tn < 2; ++tn) {
          int d = tn * 16 + l15;                     // 0..31
          float a = acc[tm][tn][r];                  // x[d]
          float b = acc[tm][tn + 2][r];              // x[d+32]
          float c1 = cos_t[p * 64 + d],      s1 = sin_t[p * 64 + d];
          float c2 = cos_t[p * 64 + d + 32], s2 = sin_t[p * 64 + d + 32];
          v[tn]     = a * c1 - b * s1;
          v[tn + 2] = b * c2 + a * s2;
        }
      }
      #pragma unroll
      for (int tn = 0; tn < 4; ++tn) {
        int col = n0 + wn + tn * 16 + l15;
        if (HALF_OUT)
          ((_Float16*)Cv)[(size_t)row * N + col] = (_Float16)v[tn];
        else
          ((float*)Cv)[(size_t)row * N + col] = v[tn];
      }
    }
  }
}

// ---------------- 64x64 MFMA GEMM (kept for the small output projection) ----------------
template <bool HALF_OUT>
__global__ __launch_bounds__(256) void k_gemm(const _Float16* __restrict__ A,
                                              const _Float16* __restrict__ Bt,
                                              void* __restrict__ Cv, int M, int N, int K) {
  __shared__ _Float16 As[64][72];
  __shared__ _Float16 Bs[64][72];
  const int tid = threadIdx.x;
  const int lane = tid & 63;
  const int wave = tid >> 6;
  const int wm = (wave >> 1) * 32;
  const int wn = (wave & 1) * 32;
  const int row16 = lane & 15;
  const int q4 = lane >> 4;
  const int m0 = blockIdx.x * 64;
  const int n0 = blockIdx.y * 64;

  floatx4 acc[2][2];
  #pragma unroll
  for (int a = 0; a < 2; ++a)
    #pragma unroll
    for (int b = 0; b < 2; ++b) acc[a][b] = (floatx4){0.f, 0.f, 0.f, 0.f};

  for (int k0 = 0; k0 < K; k0 += 64) {
    __syncthreads();
    #pragma unroll
    for (int rep = 0; rep < 2; ++rep) {
      int c = tid + rep * 256;
      int r = c >> 3, q = c & 7;
      *(half8*)&As[r][q * 8] = *(const half8*)(A + (size_t)(m0 + r) * K + k0 + q * 8);
      *(half8*)&Bs[r][q * 8] = *(const half8*)(Bt + (size_t)(n0 + r) * K + k0 + q * 8);
    }
    __syncthreads();
    #pragma unroll
    for (int kk = 0; kk < 64; kk += 32) {
      half8 a0 = *(const half8*)&As[wm + row16][kk + q4 * 8];
      half8 a1 = *(const half8*)&As[wm + 16 + row16][kk + q4 * 8];
      half8 b0 = *(const half8*)&Bs[wn + row16][kk + q4 * 8];
      half8 b1 = *(const half8*)&Bs[wn + 16 + row16][kk + q4 * 8];
      acc[0][0] = __builtin_amdgcn_mfma_f32_16x16x32_f16(a0, b0, acc[0][0], 0, 0, 0);
      acc[0][1] = __builtin_amdgcn_mfma_f32_16x16x32_f16(a0, b1, acc[0][1], 0, 0, 0);
      acc[1][0] = __builtin_amdgcn_mfma_f32_16x16x32_f16(a1, b0, acc[1][0], 0, 0, 0);
      acc[1][1] = __builtin_amdgcn_mfma_f32_16x16x32_f16(a1, b1, acc[1][1], 0, 0, 0);
    }
  }
  #pragma unroll
  for (int im = 0; im < 2; ++im)
    #pragma unroll
    for (int in = 0; in < 2; ++in)
      #pragma unroll
      for (int r = 0; r < 4; ++r) {
        int row = m0 + wm + im * 16 + q4 * 4 + r;
        int col = n0 + wn + in * 16 + row16;
        if (HALF_OUT)
          ((_Float16*)Cv)[(size_t)row * N + col] = (_Float16)acc[im][in][r];
        else
          ((float*)Cv)[(size_t)row * N + col] = acc[im][in][r];
      }
}

// ---------------- MFMA flash attention: tiles 4..31 (rows 256..2047) ----------------
__global__ __launch_bounds__(256, 4) void k_attn_main(const _Float16* __restrict__ proj,
                                                      _Float16* __restrict__ out) {
  const int i0 = (blockIdx.x + 4) * 64;
  const int jlo = i0 - 256;
  const int hb = blockIdx.y * 64;
  const int tid = threadIdx.x;
  const int lane = tid & 63;
  const int w = tid >> 6;
  const int l15 = lane & 15;
  const int q4 = lane >> 4;

  __shared__ _Float16 Qs[64][72];
  __shared__ _Float16 Kc[64][72];
  __shared__ _Float16 Vtc[64][72];
  __shared__ _Float16 Ps[64][72];
  __shared__ _Float16 kg_s[4][64];
  __shared__ _Float16 vg_s[4][64];
  __shared__ float svg_s[64];
  __shared__ float pg_s[4][64];

  #pragma unroll
  for (int rep = 0; rep < 2; ++rep) {
    int c = tid + rep * 256;
    int r = c >> 3, q = c & 7;
    *(half8*)&Qs[r][q * 8] = *(const half8*)(proj + (size_t)(i0 + r) * PW + hb + q * 8);
  }
  {
    int g = tid >> 6, c2 = tid & 63;
    kg_s[g][c2] = proj[(size_t)g * PW + 3072 + hb + c2];
    vg_s[g][c2] = proj[(size_t)g * PW + 4096 + hb + c2];
    if (tid < 64) {
      float s = 0.f;
      #pragma unroll
      for (int g2 = 0; g2 < 4; ++g2) s += (float)proj[(size_t)g2 * PW + 2048 + hb + tid];
      svg_s[tid] = s;
    }
  }
  __syncthreads();

  {
    int rid = lane >> 2, part = lane & 3;
    int ro = w * 16 + rid;
    float sg[4];
    #pragma unroll
    for (int g = 0; g < 4; ++g) {
      float acc = 0.f;
      #pragma unroll
      for (int u = 0; u < 16; ++u)
        acc += (float)Qs[ro][part * 16 + u] * (float)kg_s[g][part * 16 + u];
      acc += __shfl_xor(acc, 1, 64);
      acc += __shfl_xor(acc, 2, 64);
      sg[g] = acc * 0.125f;
    }
    float mg = fmaxf(fmaxf(sg[0], sg[1]), fmaxf(sg[2], sg[3]));
    float dg = 0.f;
    #pragma unroll
    for (int g = 0; g < 4; ++g) dg += __expf(sg[g] - mg);
    pg_s[part][ro] = __expf(sg[part] - mg) / dg;
  }

  half8 qf0 = *(const half8*)&Qs[w * 16 + l15][q4 * 8];
  half8 qf1 = *(const half8*)&Qs[w * 16 + l15][32 + q4 * 8];

  float m_r[4] = {0.f, 0.f, 0.f, 0.f};
  float l_r[4] = {4.f, 4.f, 4.f, 4.f};
  floatx4 oacc[4];
  #pragma unroll
  for (int cb = 0; cb < 4; ++cb) oacc[cb] = (floatx4){0.f, 0.f, 0.f, 0.f};

  for (int cc = 0; cc < 5; ++cc) {
    const int jbase = jlo + cc * 64;
    __syncthreads();
    #pragma unroll
    for (int rep = 0; rep < 2; ++rep) {
      int c = tid + rep * 256;
      int r = c >> 3, q = c & 7;
      *(half8*)&Kc[r][q * 8] =
          *(const half8*)(proj + (size_t)(jbase + r) * PW + 1024 + hb + q * 8);
    }
    #pragma unroll
    for (int it = 0; it < 16; ++it) {
      int e = tid + it * 256;
      int d = e & 63, j = e >> 6;
      Vtc[d][j] = proj[(size_t)(jbase + j) * PW + 2048 + hb + d];
    }
    __syncthreads();

    float sc[4][4];
    #pragma unroll
    for (int cb = 0; cb < 4; ++cb) {
      half8 b0 = *(const half8*)&Kc[cb * 16 + l15][q4 * 8];
      half8 b1 = *(const half8*)&Kc[cb * 16 + l15][32 + q4 * 8];
      floatx4 a = (floatx4){0.f, 0.f, 0.f, 0.f};
      a = __builtin_amdgcn_mfma_f32_16x16x32_f16(qf0, b0, a, 0, 0, 0);
      a = __builtin_amdgcn_mfma_f32_16x16x32_f16(qf1, b1, a, 0, 0, 0);
      #pragma unroll
      for (int r = 0; r < 4; ++r) sc[cb][r] = a[r];
    }

    #pragma unroll
    for (int r = 0; r < 4; ++r) {
      int ri = w * 16 + q4 * 4 + r;
      float rowmax = -1e30f;
      #pragma unroll
      for (int cb = 0; cb < 4; ++cb) {
        int jjg = cc * 64 + cb * 16 + l15;
        bool valid = (jjg >= ri) && (jjg <= ri + 256);
        float s = valid ? sc[cb][r] * 0.125f : -1e30f;
        sc[cb][r] = s;
        rowmax = fmaxf(rowmax, s);
      }
      #pragma unroll
      for (int off = 1; off < 16; off <<= 1)
        rowmax = fmaxf(rowmax, __shfl_xor(rowmax, off, 64));
      float m_new = fmaxf(m_r[r], rowmax);
      float alpha = __expf(m_r[r] - m_new);
      float rs = 0.f;
      #pragma unroll
      for (int cb = 0; cb < 4; ++cb) {
        float p = __expf(sc[cb][r] - m_new);
        Ps[w * 16 + q4 * 4 + r][cb * 16 + l15] = (_Float16)p;
        rs += p;
      }
      #pragma unroll
      for (int off = 1; off < 16; off <<= 1) rs += __shfl_xor(rs, off, 64);
      l_r[r] = l_r[r] * alpha + rs;
      m_r[r] = m_new;
      #pragma unroll
      for (int cb = 0; cb < 4; ++cb) oacc[cb][r] *= alpha;
    }

    half8 pf0 = *(const half8*)&Ps[w * 16 + l15][q4 * 8];
    half8 pf1 = *(const half8*)&Ps[w * 16 + l15][32 + q4 * 8];
    #pragma unroll
    for (int cb = 0; cb < 4; ++cb) {
      half8 v0 = *(const half8*)&Vtc[cb * 16 + l15][q4 * 8];
      half8 v1 = *(const half8*)&Vtc[cb * 16 + l15][32 + q4 * 8];
      oacc[cb] = __builtin_amdgcn_mfma_f32_16x16x32_f16(pf0, v0, oacc[cb], 0, 0, 0);
      oacc[cb] = __builtin_amdgcn_mfma_f32_16x16x32_f16(pf1, v1, oacc[cb], 0, 0, 0);
    }
  }

  #pragma unroll
  for (int r = 0; r < 4; ++r) {
    int ri = w * 16 + q4 * 4 + r;
    float e0 = __expf(-m_r[r]);
    float inv = 1.f / l_r[r];
    #pragma unroll
    for (int cb = 0; cb < 4; ++cb) {
      int col = cb * 16 + l15;
      float ol = (oacc[cb][r] + e0 * svg_s[col]) * inv;
      float og = 0.f;
      #pragma unroll
      for (int g = 0; g < 4; ++g) og += pg_s[g][ri] * (float)vg_s[g][col];
      out[(size_t)(i0 + ri) * DMODEL + hb + col] = (_Float16)(ol + og);
    }
  }
}

// ---------------- early rows (i < 260) ----------------
__device__ __forceinline__ float wave_sum(float v) {
  #pragma unroll
  for (int off = 32; off; off >>= 1) v += __shfl_xor(v, off, 64);
  return v;
}

__global__ __launch_bounds__(64) void k_attn_early(const _Float16* __restrict__ proj,
                                                   _Float16* __restrict__ out) {
  const int i = blockIdx.x;
  const int h = blockIdx.y;
  const int lane = threadIdx.x;
  const float scale = 0.125f;
  const int hb = h * 64;
  float qv = (float)proj[(size_t)i * PW + hb + lane];

  float sg[4];
  #pragma unroll
  for (int g = 0; g < 4; ++g) {
    float kgv = (float)proj[(size_t)g * PW + 3072 + hb + lane];
    sg[g] = wave_sum(qv * kgv) * scale;
  }
  float mg = fmaxf(fmaxf(sg[0], sg[1]), fmaxf(sg[2], sg[3]));
  float dg = 0.f, og = 0.f;
  #pragma unroll
  for (int g = 0; g < 4; ++g) {
    float p = __expf(sg[g] - mg);
    dg += p;
    og += p * (float)proj[(size_t)g * PW + 4096 + hb + lane];
  }
  og /= dg;

  int jmin = (i >= 256) ? (i - 256) : 0;
  int jmax = (i < 3) ? i : 3;
  float acc = 0.f;
  for (int j = jmin; j <= jmax; ++j)
    acc += (float)proj[(size_t)j * PW + 2048 + hb + lane];
  float ol = acc / (float)(jmax - jmin + 1);

  out[(size_t)i * DMODEL + hb + lane] = (_Float16)(ol + og);
}

// ---------------- launcher ----------------
extern "C" void kernel_launch(void* const* d_in, const int* in_sizes, int n_in,
                              void* d_out, int out_size, void* d_ws, size_t ws_size,
                              hipStream_t stream) {
  const float* x     = (const float*)d_in[0];
  const float* cos_t = (const float*)d_in[1];
  const float* sin_t = (const float*)d_in[2];
  const int*   pos   = (const int*)d_in[3];
  const float* Wqs   = (const float*)d_in[4];
  const float* Wks   = (const float*)d_in[5];
  const float* Wvs   = (const float*)d_in[6];
  const float* Wkg   = (const float*)d_in[8];
  const float* Wvg   = (const float*)d_in[9];
  const float* Wo    = (const float*)d_in[10];
  float* out = (float*)d_out;

  char* ws = (char*)d_ws;
  _Float16* xh   = (_Float16*)(ws);                        //  4 MB
  _Float16* wcat = (_Float16*)(ws + (4u << 20));           // 10 MB
  _Float16* wot  = (_Float16*)(ws + (14u << 20));          //  2 MB
  _Float16* proj = (_Float16*)(ws + (16u << 20));          // 20 MB
  _Float16* attn = (_Float16*)(ws + (36u << 20));          //  4 MB

  k_cvt_x<<<(SEQ * DMODEL + 255) / 256, 256, 0, stream>>>(x, xh, SEQ * DMODEL);
  k_transpose_w<<<dim3(32, 32, 6), dim3(32, 8), 0, stream>>>(Wqs, Wks, Wvs, Wkg, Wvg, Wo,
                                                             wcat, wot);
  // proj GEMM with fused RoPE on q|k columns (n < 2048)
  k_gemm128<true, true><<<dim3(SEQ / 128, PW / 128), 256, 0, stream>>>(
      xh, wcat, proj, cos_t, sin_t, pos, SEQ, PW, DMODEL);
  k_attn_main<<<dim3(28, NHEADS), 256, 0, stream>>>(proj, attn);
  k_attn_early<<<dim3(260, NHEADS), 64, 0, stream>>>(proj, attn);
  k_gemm<false><<<dim3(SEQ / 64, DMODEL / 64), 256, 0, stream>>>(attn, wot, out, SEQ, DMODEL,
                                                                 DMODEL);
}

// Round 4
// 190.599 us; speedup vs baseline: 2.5541x; 1.0294x over previous
//
#include <hip/hip_runtime.h>

typedef _Float16 half8 __attribute__((ext_vector_type(8)));
typedef float floatx4 __attribute__((ext_vector_type(4)));

#define SEQ 2048
#define DMODEL 1024
#define NHEADS 16
#define HEADDIM 64
#define PW 5120   // proj row width: q|k|v|kg|vg

// ---------------- fused prep: x fp32->fp16 + 6 weight transposes (vectorized) ----------------
// blocks 0..1023: convert x (2048 elements each, float4 in / half8 out)
// blocks 1024..2559: 64x64 transpose tiles, 256 per matrix; float4 loads -> LDS -> half8 stores
__global__ __launch_bounds__(256) void k_prep(
    const float* __restrict__ x,
    const float* __restrict__ w0, const float* __restrict__ w1, const float* __restrict__ w2,
    const float* __restrict__ w3, const float* __restrict__ w4, const float* __restrict__ w5,
    _Float16* __restrict__ xh, _Float16* __restrict__ wcat, _Float16* __restrict__ wot) {
  const int tid = threadIdx.x;
  const int b = blockIdx.x;
  if (b < 1024) {
    int base = b * 2048 + tid * 8;
    floatx4 f0 = *(const floatx4*)(x + base);
    floatx4 f1 = *(const floatx4*)(x + base + 4);
    half8 h;
    #pragma unroll
    for (int e = 0; e < 4; ++e) { h[e] = (_Float16)f0[e]; h[e + 4] = (_Float16)f1[e]; }
    *(half8*)(xh + base) = h;
    return;
  }
  __shared__ _Float16 T[64][72];  // T[n][k]
  int t = b - 1024;
  int z = t >> 8;                 // matrix 0..5
  int tile = t & 255;             // 16x16 tiles of 64x64
  int k0 = (tile >> 4) * 64, n0 = (tile & 15) * 64;
  const float* W = (z == 0) ? w0 : (z == 1) ? w1 : (z == 2) ? w2
                 : (z == 3) ? w3 : (z == 4) ? w4 : w5;
  _Float16* dst = (z < 5) ? (wcat + (size_t)z * 1024 * 1024) : wot;

  int lr = tid >> 2, c0 = (tid & 3) * 16;  // load: row k0+lr, cols n0+c0..c0+15
  #pragma unroll
  for (int i = 0; i < 4; ++i) {
    floatx4 f = *(const floatx4*)(W + (size_t)(k0 + lr) * DMODEL + n0 + c0 + i * 4);
    #pragma unroll
    for (int e = 0; e < 4; ++e) T[c0 + i * 4 + e][lr] = (_Float16)f[e];
  }
  __syncthreads();
  int nr = tid >> 2, s0 = (tid & 3) * 16;  // store: dst row n0+nr, k-cols k0+s0..s0+15
  #pragma unroll
  for (int i = 0; i < 2; ++i) {
    half8 h = *(const half8*)&T[nr][s0 + i * 8];
    *(half8*)(dst + (size_t)(n0 + nr) * DMODEL + k0 + s0 + i * 8) = h;
  }
}

// ---------------- m97-style 128x128 MFMA GEMM, global_load_lds + XOR swizzle ----------------
// FUSE_ROPE: for n0 < 2048 (q|k), apply RoPE on fp32 acc in the epilogue;
// pair d <-> d+32 is acc[tm][tn] <-> acc[tm][tn^2] in the SAME lane.
template <bool HALF_OUT, bool FUSE_ROPE>
__global__ __launch_bounds__(256) void k_gemm128(const _Float16* __restrict__ A,
                                                 const _Float16* __restrict__ Bt,
                                                 void* __restrict__ Cv,
                                                 const float* __restrict__ cos_t,
                                                 const float* __restrict__ sin_t,
                                                 const int* __restrict__ pos,
                                                 int M, int N, int K) {
  __shared__ _Float16 As[128][64];
  __shared__ _Float16 Bs[128][64];
  const int tid = threadIdx.x;
  const int lane = tid & 63;
  const int w = tid >> 6;
  const int wm = (w >> 1) * 64;
  const int wn = (w & 1) * 64;
  const int l15 = lane & 15;
  const int q4 = lane >> 4;
  const int m0 = blockIdx.x * 128;
  const int n0 = blockIdx.y * 128;

  floatx4 acc[4][4];
  #pragma unroll
  for (int i = 0; i < 4; ++i)
    #pragma unroll
    for (int j = 0; j < 4; ++j) acc[i][j] = (floatx4){0.f, 0.f, 0.f, 0.f};

  _Float16* asBase = &As[0][0];
  _Float16* bsBase = &Bs[0][0];
  const int swz = l15 & 7;

  for (int k0 = 0; k0 < K; k0 += 64) {
    __syncthreads();
    #pragma unroll
    for (int it = 0; it < 4; ++it) {
      int c = it * 256 + tid;
      int r = c >> 3, cc = c & 7;
      int g = cc ^ (r & 7);
      __builtin_amdgcn_global_load_lds(
          (const __attribute__((address_space(1))) void*)(A + (size_t)(m0 + r) * K + k0 + g * 8),
          (__attribute__((address_space(3))) void*)(asBase + (it * 256 + w * 64) * 8),
          16, 0, 0);
      __builtin_amdgcn_global_load_lds(
          (const __attribute__((address_space(1))) void*)(Bt + (size_t)(n0 + r) * K + k0 + g * 8),
          (__attribute__((address_space(3))) void*)(bsBase + (it * 256 + w * 64) * 8),
          16, 0, 0);
    }
    __syncthreads();

    #pragma unroll
    for (int kk = 0; kk < 2; ++kk) {
      int q = kk * 4 + q4;
      half8 af[4], bf[4];
      #pragma unroll
      for (int t = 0; t < 4; ++t) {
        int ar = wm + t * 16 + l15;
        af[t] = *(const half8*)(asBase + (size_t)ar * 64 + ((q ^ swz) * 8));
        int br = wn + t * 16 + l15;
        bf[t] = *(const half8*)(bsBase + (size_t)br * 64 + ((q ^ swz) * 8));
      }
      #pragma unroll
      for (int i = 0; i < 4; ++i)
        #pragma unroll
        for (int j = 0; j < 4; ++j)
          acc[i][j] = __builtin_amdgcn_mfma_f32_16x16x32_f16(af[i], bf[j], acc[i][j], 0, 0, 0);
    }
  }

  #pragma unroll
  for (int tm = 0; tm < 4; ++tm) {
    #pragma unroll
    for (int r = 0; r < 4; ++r) {
      int row = m0 + wm + tm * 16 + q4 * 4 + r;
      float v[4];
      #pragma unroll
      for (int tn = 0; tn < 4; ++tn) v[tn] = acc[tm][tn][r];
      if (FUSE_ROPE && n0 < 2048) {
        int p = pos[row];
        #pragma unroll
        for (int tn = 0; tn < 2; ++tn) {
          int d = tn * 16 + l15;
          float a = acc[tm][tn][r];
          float bvv = acc[tm][tn + 2][r];
          float c1 = cos_t[p * 64 + d],      s1 = sin_t[p * 64 + d];
          float c2 = cos_t[p * 64 + d + 32], s2 = sin_t[p * 64 + d + 32];
          v[tn]     = a * c1 - bvv * s1;
          v[tn + 2] = bvv * c2 + a * s2;
        }
      }
      #pragma unroll
      for (int tn = 0; tn < 4; ++tn) {
        int col = n0 + wn + tn * 16 + l15;
        if (HALF_OUT)
          ((_Float16*)Cv)[(size_t)row * N + col] = (_Float16)v[tn];
        else
          ((float*)Cv)[(size_t)row * N + col] = v[tn];
      }
    }
  }
}

// ---------------- 64x64 MFMA GEMM (output projection; 512 blocks) ----------------
template <bool HALF_OUT>
__global__ __launch_bounds__(256) void k_gemm(const _Float16* __restrict__ A,
                                              const _Float16* __restrict__ Bt,
                                              void* __restrict__ Cv, int M, int N, int K) {
  __shared__ _Float16 As[64][72];
  __shared__ _Float16 Bs[64][72];
  const int tid = threadIdx.x;
  const int lane = tid & 63;
  const int wave = tid >> 6;
  const int wm = (wave >> 1) * 32;
  const int wn = (wave & 1) * 32;
  const int row16 = lane & 15;
  const int q4 = lane >> 4;
  const int m0 = blockIdx.x * 64;
  const int n0 = blockIdx.y * 64;

  floatx4 acc[2][2];
  #pragma unroll
  for (int a = 0; a < 2; ++a)
    #pragma unroll
    for (int b = 0; b < 2; ++b) acc[a][b] = (floatx4){0.f, 0.f, 0.f, 0.f};

  for (int k0 = 0; k0 < K; k0 += 64) {
    __syncthreads();
    #pragma unroll
    for (int rep = 0; rep < 2; ++rep) {
      int c = tid + rep * 256;
      int r = c >> 3, q = c & 7;
      *(half8*)&As[r][q * 8] = *(const half8*)(A + (size_t)(m0 + r) * K + k0 + q * 8);
      *(half8*)&Bs[r][q * 8] = *(const half8*)(Bt + (size_t)(n0 + r) * K + k0 + q * 8);
    }
    __syncthreads();
    #pragma unroll
    for (int kk = 0; kk < 64; kk += 32) {
      half8 a0 = *(const half8*)&As[wm + row16][kk + q4 * 8];
      half8 a1 = *(const half8*)&As[wm + 16 + row16][kk + q4 * 8];
      half8 b0 = *(const half8*)&Bs[wn + row16][kk + q4 * 8];
      half8 b1 = *(const half8*)&Bs[wn + 16 + row16][kk + q4 * 8];
      acc[0][0] = __builtin_amdgcn_mfma_f32_16x16x32_f16(a0, b0, acc[0][0], 0, 0, 0);
      acc[0][1] = __builtin_amdgcn_mfma_f32_16x16x32_f16(a0, b1, acc[0][1], 0, 0, 0);
      acc[1][0] = __builtin_amdgcn_mfma_f32_16x16x32_f16(a1, b0, acc[1][0], 0, 0, 0);
      acc[1][1] = __builtin_amdgcn_mfma_f32_16x16x32_f16(a1, b1, acc[1][1], 0, 0, 0);
    }
  }
  #pragma unroll
  for (int im = 0; im < 2; ++im)
    #pragma unroll
    for (int in = 0; in < 2; ++in)
      #pragma unroll
      for (int r = 0; r < 4; ++r) {
        int row = m0 + wm + im * 16 + q4 * 4 + r;
        int col = n0 + wn + in * 16 + row16;
        if (HALF_OUT)
          ((_Float16*)Cv)[(size_t)row * N + col] = (_Float16)acc[im][in][r];
        else
          ((float*)Cv)[(size_t)row * N + col] = acc[im][in][r];
      }
}

// ---------------- merged attention ----------------
// grid.x: 0..27 = MFMA flash tiles (rows 256..2047, tile-0 skips rows 256..259);
//         28..92 = early rows (i < 260, wave per row, absorbed-1e9 uniform average).
__global__ __launch_bounds__(256, 4) void k_attn(const _Float16* __restrict__ proj,
                                                 _Float16* __restrict__ out) {
  const int tid = threadIdx.x;
  const int hb = blockIdx.y * 64;

  if (blockIdx.x >= 28) {
    // ---- early rows: i in 0..259, one wave per row ----
    const int i = (blockIdx.x - 28) * 4 + (tid >> 6);
    const int lane = tid & 63;
    const float scale = 0.125f;
    float qv = (float)proj[(size_t)i * PW + hb + lane];

    float sg[4];
    #pragma unroll
    for (int g = 0; g < 4; ++g) {
      float kgv = (float)proj[(size_t)g * PW + 3072 + hb + lane];
      float v = qv * kgv;
      #pragma unroll
      for (int off = 32; off; off >>= 1) v += __shfl_xor(v, off, 64);
      sg[g] = v * scale;
    }
    float mg = fmaxf(fmaxf(sg[0], sg[1]), fmaxf(sg[2], sg[3]));
    float dg = 0.f, og = 0.f;
    #pragma unroll
    for (int g = 0; g < 4; ++g) {
      float p = __expf(sg[g] - mg);
      dg += p;
      og += p * (float)proj[(size_t)g * PW + 4096 + hb + lane];
    }
    og /= dg;

    int jmin = (i >= 256) ? (i - 256) : 0;
    int jmax = (i < 3) ? i : 3;
    float acc = 0.f;
    for (int j = jmin; j <= jmax; ++j)
      acc += (float)proj[(size_t)j * PW + 2048 + hb + lane];
    float ol = acc / (float)(jmax - jmin + 1);

    out[(size_t)i * DMODEL + hb + lane] = (_Float16)(ol + og);
    return;
  }

  // ---- MFMA flash path ----
  const int i0 = (blockIdx.x + 4) * 64;
  const int jlo = i0 - 256;
  const int lane = tid & 63;
  const int w = tid >> 6;
  const int l15 = lane & 15;
  const int q4 = lane >> 4;

  __shared__ _Float16 Qs[64][72];
  __shared__ _Float16 Kc[64][72];
  __shared__ _Float16 Vtc[64][72];
  __shared__ _Float16 Ps[64][72];
  __shared__ _Float16 kg_s[4][64];
  __shared__ _Float16 vg_s[4][64];
  __shared__ float svg_s[64];
  __shared__ float pg_s[4][64];

  #pragma unroll
  for (int rep = 0; rep < 2; ++rep) {
    int c = tid + rep * 256;
    int r = c >> 3, q = c & 7;
    *(half8*)&Qs[r][q * 8] = *(const half8*)(proj + (size_t)(i0 + r) * PW + hb + q * 8);
  }
  {
    int g = tid >> 6, c2 = tid & 63;
    kg_s[g][c2] = proj[(size_t)g * PW + 3072 + hb + c2];
    vg_s[g][c2] = proj[(size_t)g * PW + 4096 + hb + c2];
    if (tid < 64) {
      float s = 0.f;
      #pragma unroll
      for (int g2 = 0; g2 < 4; ++g2) s += (float)proj[(size_t)g2 * PW + 2048 + hb + tid];
      svg_s[tid] = s;
    }
  }
  __syncthreads();

  {
    int rid = lane >> 2, part = lane & 3;
    int ro = w * 16 + rid;
    float sg[4];
    #pragma unroll
    for (int g = 0; g < 4; ++g) {
      float acc = 0.f;
      #pragma unroll
      for (int u = 0; u < 16; ++u)
        acc += (float)Qs[ro][part * 16 + u] * (float)kg_s[g][part * 16 + u];
      acc += __shfl_xor(acc, 1, 64);
      acc += __shfl_xor(acc, 2, 64);
      sg[g] = acc * 0.125f;
    }
    float mg = fmaxf(fmaxf(sg[0], sg[1]), fmaxf(sg[2], sg[3]));
    float dg = 0.f;
    #pragma unroll
    for (int g = 0; g < 4; ++g) dg += __expf(sg[g] - mg);
    pg_s[part][ro] = __expf(sg[part] - mg) / dg;
  }

  half8 qf0 = *(const half8*)&Qs[w * 16 + l15][q4 * 8];
  half8 qf1 = *(const half8*)&Qs[w * 16 + l15][32 + q4 * 8];

  float m_r[4] = {0.f, 0.f, 0.f, 0.f};
  float l_r[4] = {4.f, 4.f, 4.f, 4.f};  // 4 global cols, fp32 score exactly 0
  floatx4 oacc[4];
  #pragma unroll
  for (int cb = 0; cb < 4; ++cb) oacc[cb] = (floatx4){0.f, 0.f, 0.f, 0.f};

  for (int cc = 0; cc < 5; ++cc) {
    const int jbase = jlo + cc * 64;
    __syncthreads();
    // K chunk: vectorized row-major
    #pragma unroll
    for (int rep = 0; rep < 2; ++rep) {
      int c = tid + rep * 256;
      int r = c >> 3, q = c & 7;
      *(half8*)&Kc[r][q * 8] =
          *(const half8*)(proj + (size_t)(jbase + r) * PW + 1024 + hb + q * 8);
    }
    // V chunk transposed: half8 global loads (1KB/wave), scalar LDS scatter
    #pragma unroll
    for (int it = 0; it < 2; ++it) {
      int idx = it * 256 + tid;                    // bits: [2:0]=j-low [5:3]=d-octet [8:6]=j-high
      int j = (idx & 7) + ((idx >> 6) << 3);
      int d0 = ((idx >> 3) & 7) * 8;
      half8 vv = *(const half8*)(proj + (size_t)(jbase + j) * PW + 2048 + hb + d0);
      #pragma unroll
      for (int u = 0; u < 8; ++u) Vtc[d0 + u][j] = vv[u];
    }
    __syncthreads();

    float sc[4][4];
    #pragma unroll
    for (int cb = 0; cb < 4; ++cb) {
      half8 b0 = *(const half8*)&Kc[cb * 16 + l15][q4 * 8];
      half8 b1 = *(const half8*)&Kc[cb * 16 + l15][32 + q4 * 8];
      floatx4 a = (floatx4){0.f, 0.f, 0.f, 0.f};
      a = __builtin_amdgcn_mfma_f32_16x16x32_f16(qf0, b0, a, 0, 0, 0);
      a = __builtin_amdgcn_mfma_f32_16x16x32_f16(qf1, b1, a, 0, 0, 0);
      #pragma unroll
      for (int r = 0; r < 4; ++r) sc[cb][r] = a[r];
    }

    #pragma unroll
    for (int r = 0; r < 4; ++r) {
      int ri = w * 16 + q4 * 4 + r;
      float rowmax = -1e30f;
      #pragma unroll
      for (int cb = 0; cb < 4; ++cb) {
        int jjg = cc * 64 + cb * 16 + l15;
        bool valid = (jjg >= ri) && (jjg <= ri + 256);
        float s = valid ? sc[cb][r] * 0.125f : -1e30f;
        sc[cb][r] = s;
        rowmax = fmaxf(rowmax, s);
      }
      #pragma unroll
      for (int off = 1; off < 16; off <<= 1)
        rowmax = fmaxf(rowmax, __shfl_xor(rowmax, off, 64));
      float m_new = fmaxf(m_r[r], rowmax);
      float alpha = __expf(m_r[r] - m_new);
      float rs = 0.f;
      #pragma unroll
      for (int cb = 0; cb < 4; ++cb) {
        float p = __expf(sc[cb][r] - m_new);
        Ps[w * 16 + q4 * 4 + r][cb * 16 + l15] = (_Float16)p;
        rs += p;
      }
      #pragma unroll
      for (int off = 1; off < 16; off <<= 1) rs += __shfl_xor(rs, off, 64);
      l_r[r] = l_r[r] * alpha + rs;
      m_r[r] = m_new;
      #pragma unroll
      for (int cb = 0; cb < 4; ++cb) oacc[cb][r] *= alpha;
    }

    half8 pf0 = *(const half8*)&Ps[w * 16 + l15][q4 * 8];
    half8 pf1 = *(const half8*)&Ps[w * 16 + l15][32 + q4 * 8];
    #pragma unroll
    for (int cb = 0; cb < 4; ++cb) {
      half8 v0 = *(const half8*)&Vtc[cb * 16 + l15][q4 * 8];
      half8 v1 = *(const half8*)&Vtc[cb * 16 + l15][32 + q4 * 8];
      oacc[cb] = __builtin_amdgcn_mfma_f32_16x16x32_f16(pf0, v0, oacc[cb], 0, 0, 0);
      oacc[cb] = __builtin_amdgcn_mfma_f32_16x16x32_f16(pf1, v1, oacc[cb], 0, 0, 0);
    }
  }

  #pragma unroll
  for (int r = 0; r < 4; ++r) {
    int ri = w * 16 + q4 * 4 + r;
    if (i0 + ri < 260) continue;  // rows 256..259 handled by the early path
    float e0 = __expf(-m_r[r]);
    float inv = 1.f / l_r[r];
    #pragma unroll
    for (int cb = 0; cb < 4; ++cb) {
      int col = cb * 16 + l15;
      float ol = (oacc[cb][r] + e0 * svg_s[col]) * inv;
      float og = 0.f;
      #pragma unroll
      for (int g = 0; g < 4; ++g) og += pg_s[g][ri] * (float)vg_s[g][col];
      out[(size_t)(i0 + ri) * DMODEL + hb + col] = (_Float16)(ol + og);
    }
  }
}

// ---------------- launcher ----------------
extern "C" void kernel_launch(void* const* d_in, const int* in_sizes, int n_in,
                              void* d_out, int out_size, void* d_ws, size_t ws_size,
                              hipStream_t stream) {
  const float* x     = (const float*)d_in[0];
  const float* cos_t = (const float*)d_in[1];
  const float* sin_t = (const float*)d_in[2];
  const int*   pos   = (const int*)d_in[3];
  const float* Wqs   = (const float*)d_in[4];
  const float* Wks   = (const float*)d_in[5];
  const float* Wvs   = (const float*)d_in[6];
  const float* Wkg   = (const float*)d_in[8];
  const float* Wvg   = (const float*)d_in[9];
  const float* Wo    = (const float*)d_in[10];
  float* out = (float*)d_out;

  char* ws = (char*)d_ws;
  _Float16* xh   = (_Float16*)(ws);                        //  4 MB
  _Float16* wcat = (_Float16*)(ws + (4u << 20));           // 10 MB
  _Float16* wot  = (_Float16*)(ws + (14u << 20));          //  2 MB
  _Float16* proj = (_Float16*)(ws + (16u << 20));          // 20 MB
  _Float16* attn = (_Float16*)(ws + (36u << 20));          //  4 MB

  k_prep<<<2560, 256, 0, stream>>>(x, Wqs, Wks, Wvs, Wkg, Wvg, Wo, xh, wcat, wot);
  k_gemm128<true, true><<<dim3(SEQ / 128, PW / 128), 256, 0, stream>>>(
      xh, wcat, proj, cos_t, sin_t, pos, SEQ, PW, DMODEL);
  k_attn<<<dim3(93, NHEADS), 256, 0, stream>>>(proj, attn);
  k_gemm<false><<<dim3(SEQ / 64, DMODEL / 64), 256, 0, stream>>>(attn, wot, out, SEQ, DMODEL,
                                                                 DMODEL);
}

// Round 5
// 183.800 us; speedup vs baseline: 2.6486x; 1.0370x over previous
//
#include <hip/hip_runtime.h>

typedef _Float16 half8 __attribute__((ext_vector_type(8)));
typedef float floatx4 __attribute__((ext_vector_type(4)));

#define SEQ 2048
#define DMODEL 1024
#define NHEADS 16
#define HEADDIM 64
#define PW 5120   // proj row width: q|k|v|kg|vg

// ---------------- fused prep: x fp32->fp16 + 6 weight transposes ----------------
__global__ __launch_bounds__(256) void k_prep(
    const float* __restrict__ x,
    const float* __restrict__ w0, const float* __restrict__ w1, const float* __restrict__ w2,
    const float* __restrict__ w3, const float* __restrict__ w4, const float* __restrict__ w5,
    _Float16* __restrict__ xh, _Float16* __restrict__ wcat, _Float16* __restrict__ wot) {
  const int tid = threadIdx.x;
  const int b = blockIdx.x;
  if (b < 1024) {
    int base = b * 2048 + tid * 8;
    floatx4 f0 = *(const floatx4*)(x + base);
    floatx4 f1 = *(const floatx4*)(x + base + 4);
    half8 h;
    #pragma unroll
    for (int e = 0; e < 4; ++e) { h[e] = (_Float16)f0[e]; h[e + 4] = (_Float16)f1[e]; }
    *(half8*)(xh + base) = h;
    return;
  }
  __shared__ _Float16 T[64][72];
  int t = b - 1024;
  int z = t >> 8;
  int tile = t & 255;
  int k0 = (tile >> 4) * 64, n0 = (tile & 15) * 64;
  const float* W = (z == 0) ? w0 : (z == 1) ? w1 : (z == 2) ? w2
                 : (z == 3) ? w3 : (z == 4) ? w4 : w5;
  _Float16* dst = (z < 5) ? (wcat + (size_t)z * 1024 * 1024) : wot;

  int lr = tid >> 2, c0 = (tid & 3) * 16;
  #pragma unroll
  for (int i = 0; i < 4; ++i) {
    floatx4 f = *(const floatx4*)(W + (size_t)(k0 + lr) * DMODEL + n0 + c0 + i * 4);
    #pragma unroll
    for (int e = 0; e < 4; ++e) T[c0 + i * 4 + e][lr] = (_Float16)f[e];
  }
  __syncthreads();
  int nr = tid >> 2, s0 = (tid & 3) * 16;
  #pragma unroll
  for (int i = 0; i < 2; ++i) {
    half8 h = *(const half8*)&T[nr][s0 + i * 8];
    *(half8*)(dst + (size_t)(n0 + nr) * DMODEL + k0 + s0 + i * 8) = h;
  }
}

// ---------------- 128x128 MFMA GEMM, BK=128, global_load_lds + XOR swizzle ----------------
// C[M,N] = A[M,K] @ Bt[N,K]^T over K-range [z*kLen, (z+1)*kLen).
// HALF_OUT: fp16 to Cv (proj path, optional fused RoPE for n0<2048).
// !HALF_OUT: fp32 partial to (z ? Cp1 : Cp0) for split-K.
template <bool HALF_OUT, bool FUSE_ROPE>
__global__ __launch_bounds__(256, 2) void k_gemm128b(
    const _Float16* __restrict__ A, const _Float16* __restrict__ Bt,
    void* __restrict__ Cv, float* __restrict__ Cp0, float* __restrict__ Cp1,
    const float* __restrict__ cos_t, const float* __restrict__ sin_t,
    const int* __restrict__ pos, int M, int N, int K, int kLen) {
  __shared__ _Float16 As[128][128];  // 32 KB
  __shared__ _Float16 Bs[128][128];  // 32 KB
  const int tid = threadIdx.x;
  const int lane = tid & 63;
  const int w = tid >> 6;
  const int wm = (w >> 1) * 64;
  const int wn = (w & 1) * 64;
  const int l15 = lane & 15;
  const int q4 = lane >> 4;
  const int m0 = blockIdx.x * 128;
  const int n0 = blockIdx.y * 128;
  const int kStart = blockIdx.z * kLen;

  floatx4 acc[4][4];
  #pragma unroll
  for (int i = 0; i < 4; ++i)
    #pragma unroll
    for (int j = 0; j < 4; ++j) acc[i][j] = (floatx4){0.f, 0.f, 0.f, 0.f};

  _Float16* asBase = &As[0][0];
  _Float16* bsBase = &Bs[0][0];
  const int swz = l15 & 7;

  for (int k0 = kStart; k0 < kStart + kLen; k0 += 128) {
    __syncthreads();
    #pragma unroll
    for (int it = 0; it < 8; ++it) {
      int c = it * 256 + tid;          // chunk 0..2047 (16B each), 16 chunks/row
      int r = c >> 4, cc = c & 15;
      int g = cc ^ (r & 7);            // swizzled global k-chunk
      __builtin_amdgcn_global_load_lds(
          (const __attribute__((address_space(1))) void*)(A + (size_t)(m0 + r) * K + k0 + g * 8),
          (__attribute__((address_space(3))) void*)(asBase + (it * 256 + w * 64) * 8),
          16, 0, 0);
      __builtin_amdgcn_global_load_lds(
          (const __attribute__((address_space(1))) void*)(Bt + (size_t)(n0 + r) * K + k0 + g * 8),
          (__attribute__((address_space(3))) void*)(bsBase + (it * 256 + w * 64) * 8),
          16, 0, 0);
    }
    __syncthreads();

    #pragma unroll
    for (int kk = 0; kk < 4; ++kk) {
      int q = kk * 4 + q4;             // global k-chunk 0..15
      half8 af[4], bf[4];
      #pragma unroll
      for (int t = 0; t < 4; ++t) {
        int ar = wm + t * 16 + l15;
        af[t] = *(const half8*)(asBase + (size_t)ar * 128 + ((q ^ swz) * 8));
        int br = wn + t * 16 + l15;
        bf[t] = *(const half8*)(bsBase + (size_t)br * 128 + ((q ^ swz) * 8));
      }
      #pragma unroll
      for (int i = 0; i < 4; ++i)
        #pragma unroll
        for (int j = 0; j < 4; ++j)
          acc[i][j] = __builtin_amdgcn_mfma_f32_16x16x32_f16(af[i], bf[j], acc[i][j], 0, 0, 0);
    }
  }

  float* P = HALF_OUT ? nullptr : (blockIdx.z ? Cp1 : Cp0);
  #pragma unroll
  for (int tm = 0; tm < 4; ++tm) {
    #pragma unroll
    for (int r = 0; r < 4; ++r) {
      int row = m0 + wm + tm * 16 + q4 * 4 + r;
      float v[4];
      #pragma unroll
      for (int tn = 0; tn < 4; ++tn) v[tn] = acc[tm][tn][r];
      if (FUSE_ROPE && n0 < 2048) {
        int p = pos[row];
        #pragma unroll
        for (int tn = 0; tn < 2; ++tn) {
          int d = tn * 16 + l15;
          float a = acc[tm][tn][r];
          float bvv = acc[tm][tn + 2][r];
          float c1 = cos_t[p * 64 + d],      s1 = sin_t[p * 64 + d];
          float c2 = cos_t[p * 64 + d + 32], s2 = sin_t[p * 64 + d + 32];
          v[tn]     = a * c1 - bvv * s1;
          v[tn + 2] = bvv * c2 + a * s2;
        }
      }
      #pragma unroll
      for (int tn = 0; tn < 4; ++tn) {
        int col = n0 + wn + tn * 16 + l15;
        if (HALF_OUT)
          ((_Float16*)Cv)[(size_t)row * N + col] = (_Float16)v[tn];
        else
          P[(size_t)row * N + col] = v[tn];
      }
    }
  }
}

// ---------------- split-K reduce: out = p0 + p1 (fp32) ----------------
__global__ __launch_bounds__(256) void k_reduce(const float* __restrict__ p0,
                                                const float* __restrict__ p1,
                                                float* __restrict__ out) {
  int i = (blockIdx.x * 256 + threadIdx.x) * 4;
  floatx4 a = *(const floatx4*)(p0 + i);
  floatx4 b = *(const floatx4*)(p1 + i);
  *(floatx4*)(out + i) = a + b;
}

// ---------------- merged attention: BM=128 flash tiles + early rows ----------------
// grid.x: 0..13 flash tiles (rows 256..2047; tile 0 write-guards rows 256..259);
//         14..78 early rows (i<260, one wave per row).
__global__ __launch_bounds__(256, 2) void k_attn(const _Float16* __restrict__ proj,
                                                 _Float16* __restrict__ out) {
  const int tid = threadIdx.x;
  const int hb = blockIdx.y * 64;

  if (blockIdx.x >= 14) {
    // ---- early rows (absorbed-1e9: uniform average over in-window global cols) ----
    const int i = (blockIdx.x - 14) * 4 + (tid >> 6);
    const int lane = tid & 63;
    const float scale = 0.125f;
    float qv = (float)proj[(size_t)i * PW + hb + lane];
    float sg[4];
    #pragma unroll
    for (int g = 0; g < 4; ++g) {
      float kgv = (float)proj[(size_t)g * PW + 3072 + hb + lane];
      float v = qv * kgv;
      #pragma unroll
      for (int off = 32; off; off >>= 1) v += __shfl_xor(v, off, 64);
      sg[g] = v * scale;
    }
    float mg = fmaxf(fmaxf(sg[0], sg[1]), fmaxf(sg[2], sg[3]));
    float dg = 0.f, og = 0.f;
    #pragma unroll
    for (int g = 0; g < 4; ++g) {
      float p = __expf(sg[g] - mg);
      dg += p;
      og += p * (float)proj[(size_t)g * PW + 4096 + hb + lane];
    }
    og /= dg;
    int jmin = (i >= 256) ? (i - 256) : 0;
    int jmax = (i < 3) ? i : 3;
    float acc = 0.f;
    for (int j = jmin; j <= jmax; ++j)
      acc += (float)proj[(size_t)j * PW + 2048 + hb + lane];
    float ol = acc / (float)(jmax - jmin + 1);
    out[(size_t)i * DMODEL + hb + lane] = (_Float16)(ol + og);
    return;
  }

  // ---- flash path: 128 Q-rows per block, 6 chunks of 64 cols ----
  const int i0 = 256 + blockIdx.x * 128;
  const int jlo = i0 - 256;
  const int lane = tid & 63;
  const int w = tid >> 6;
  const int l15 = lane & 15;
  const int q4 = lane >> 4;

  __shared__ _Float16 Qs[128][72];
  __shared__ _Float16 Kc[64][72];
  __shared__ _Float16 Vtc[64][72];
  __shared__ _Float16 Ps[128][72];
  __shared__ _Float16 kg_s[4][64];
  __shared__ _Float16 vg_s[4][64];
  __shared__ float svg_s[64];
  __shared__ float pg_s[4][128];

  #pragma unroll
  for (int rep = 0; rep < 4; ++rep) {
    int c = tid + rep * 256;
    int r = c >> 3, q = c & 7;
    *(half8*)&Qs[r][q * 8] = *(const half8*)(proj + (size_t)(i0 + r) * PW + hb + q * 8);
  }
  {
    int g = tid >> 6, c2 = tid & 63;
    kg_s[g][c2] = proj[(size_t)g * PW + 3072 + hb + c2];
    vg_s[g][c2] = proj[(size_t)g * PW + 4096 + hb + c2];
    if (tid < 64) {
      float s = 0.f;
      #pragma unroll
      for (int g2 = 0; g2 < 4; ++g2) s += (float)proj[(size_t)g2 * PW + 2048 + hb + tid];
      svg_s[tid] = s;
    }
  }
  __syncthreads();

  // global-attention probabilities for 128 rows (two 64-row passes)
  #pragma unroll
  for (int pass = 0; pass < 2; ++pass) {
    int ro = pass * 64 + w * 16 + (lane >> 2);
    int part = lane & 3;
    float sg[4];
    #pragma unroll
    for (int g = 0; g < 4; ++g) {
      float acc = 0.f;
      #pragma unroll
      for (int u = 0; u < 16; ++u)
        acc += (float)Qs[ro][part * 16 + u] * (float)kg_s[g][part * 16 + u];
      acc += __shfl_xor(acc, 1, 64);
      acc += __shfl_xor(acc, 2, 64);
      sg[g] = acc * 0.125f;
    }
    float mg = fmaxf(fmaxf(sg[0], sg[1]), fmaxf(sg[2], sg[3]));
    float dg = 0.f;
    #pragma unroll
    for (int g = 0; g < 4; ++g) dg += __expf(sg[g] - mg);
    pg_s[part][ro] = __expf(sg[part] - mg) / dg;
  }

  // wave w owns rows w*32 .. w*32+31 (two 16-row groups)
  half8 qf[2][2];
  #pragma unroll
  for (int rg = 0; rg < 2; ++rg) {
    int row = w * 32 + rg * 16 + l15;
    qf[rg][0] = *(const half8*)&Qs[row][q4 * 8];
    qf[rg][1] = *(const half8*)&Qs[row][32 + q4 * 8];
  }

  float m_r[2][4], l_r[2][4];
  floatx4 oacc[2][4];
  #pragma unroll
  for (int rg = 0; rg < 2; ++rg)
    #pragma unroll
    for (int cb = 0; cb < 4; ++cb) {
      oacc[rg][cb] = (floatx4){0.f, 0.f, 0.f, 0.f};
      m_r[rg][cb] = 0.f;     // (cb reused as r index)
      l_r[rg][cb] = 4.f;     // 4 global cols with fp32 score exactly 0
    }

  for (int cc = 0; cc < 6; ++cc) {
    const int jbase = jlo + cc * 64;
    __syncthreads();
    #pragma unroll
    for (int rep = 0; rep < 2; ++rep) {
      int c = tid + rep * 256;
      int r = c >> 3, q = c & 7;
      *(half8*)&Kc[r][q * 8] =
          *(const half8*)(proj + (size_t)(jbase + r) * PW + 1024 + hb + q * 8);
    }
    #pragma unroll
    for (int it = 0; it < 2; ++it) {
      int idx = it * 256 + tid;
      int j = (idx & 7) + ((idx >> 6) << 3);
      int d0 = ((idx >> 3) & 7) * 8;
      half8 vv = *(const half8*)(proj + (size_t)(jbase + j) * PW + 2048 + hb + d0);
      #pragma unroll
      for (int u = 0; u < 8; ++u) Vtc[d0 + u][j] = vv[u];
    }
    __syncthreads();

    #pragma unroll
    for (int rg = 0; rg < 2; ++rg) {
      float sc[4][4];
      #pragma unroll
      for (int cb = 0; cb < 4; ++cb) {
        half8 b0 = *(const half8*)&Kc[cb * 16 + l15][q4 * 8];
        half8 b1 = *(const half8*)&Kc[cb * 16 + l15][32 + q4 * 8];
        floatx4 a = (floatx4){0.f, 0.f, 0.f, 0.f};
        a = __builtin_amdgcn_mfma_f32_16x16x32_f16(qf[rg][0], b0, a, 0, 0, 0);
        a = __builtin_amdgcn_mfma_f32_16x16x32_f16(qf[rg][1], b1, a, 0, 0, 0);
        #pragma unroll
        for (int r = 0; r < 4; ++r) sc[cb][r] = a[r];
      }

      #pragma unroll
      for (int r = 0; r < 4; ++r) {
        int ri = w * 32 + rg * 16 + q4 * 4 + r;
        float rowmax = -1e30f;
        #pragma unroll
        for (int cb = 0; cb < 4; ++cb) {
          int jjg = cc * 64 + cb * 16 + l15;
          bool valid = (jjg >= ri) && (jjg <= ri + 256);
          float s = valid ? sc[cb][r] * 0.125f : -1e30f;
          sc[cb][r] = s;
          rowmax = fmaxf(rowmax, s);
        }
        #pragma unroll
        for (int off = 1; off < 16; off <<= 1)
          rowmax = fmaxf(rowmax, __shfl_xor(rowmax, off, 64));
        float m_new = fmaxf(m_r[rg][r], rowmax);
        float alpha = __expf(m_r[rg][r] - m_new);
        float rs = 0.f;
        #pragma unroll
        for (int cb = 0; cb < 4; ++cb) {
          float p = __expf(sc[cb][r] - m_new);
          Ps[ri][cb * 16 + l15] = (_Float16)p;
          rs += p;
        }
        #pragma unroll
        for (int off = 1; off < 16; off <<= 1) rs += __shfl_xor(rs, off, 64);
        l_r[rg][r] = l_r[rg][r] * alpha + rs;
        m_r[rg][r] = m_new;
        #pragma unroll
        for (int cb = 0; cb < 4; ++cb) oacc[rg][cb][r] *= alpha;
      }

      half8 pf0 = *(const half8*)&Ps[w * 32 + rg * 16 + l15][q4 * 8];
      half8 pf1 = *(const half8*)&Ps[w * 32 + rg * 16 + l15][32 + q4 * 8];
      #pragma unroll
      for (int cb = 0; cb < 4; ++cb) {
        half8 v0 = *(const half8*)&Vtc[cb * 16 + l15][q4 * 8];
        half8 v1 = *(const half8*)&Vtc[cb * 16 + l15][32 + q4 * 8];
        oacc[rg][cb] = __builtin_amdgcn_mfma_f32_16x16x32_f16(pf0, v0, oacc[rg][cb], 0, 0, 0);
        oacc[rg][cb] = __builtin_amdgcn_mfma_f32_16x16x32_f16(pf1, v1, oacc[rg][cb], 0, 0, 0);
      }
    }
  }

  #pragma unroll
  for (int rg = 0; rg < 2; ++rg)
    #pragma unroll
    for (int r = 0; r < 4; ++r) {
      int ri = w * 32 + rg * 16 + q4 * 4 + r;
      if (i0 + ri < 260) continue;  // rows 256..259 written by early path
      float e0 = __expf(-m_r[rg][r]);
      float inv = 1.f / l_r[rg][r];
      #pragma unroll
      for (int cb = 0; cb < 4; ++cb) {
        int col = cb * 16 + l15;
        float ol = (oacc[rg][cb][r] + e0 * svg_s[col]) * inv;
        float og = 0.f;
        #pragma unroll
        for (int g = 0; g < 4; ++g) og += pg_s[g][ri] * (float)vg_s[g][col];
        out[(size_t)(i0 + ri) * DMODEL + hb + col] = (_Float16)(ol + og);
      }
    }
}

// ---------------- launcher ----------------
extern "C" void kernel_launch(void* const* d_in, const int* in_sizes, int n_in,
                              void* d_out, int out_size, void* d_ws, size_t ws_size,
                              hipStream_t stream) {
  const float* x     = (const float*)d_in[0];
  const float* cos_t = (const float*)d_in[1];
  const float* sin_t = (const float*)d_in[2];
  const int*   pos   = (const int*)d_in[3];
  const float* Wqs   = (const float*)d_in[4];
  const float* Wks   = (const float*)d_in[5];
  const float* Wvs   = (const float*)d_in[6];
  const float* Wkg   = (const float*)d_in[8];
  const float* Wvg   = (const float*)d_in[9];
  const float* Wo    = (const float*)d_in[10];
  float* out = (float*)d_out;

  char* ws = (char*)d_ws;
  _Float16* xh   = (_Float16*)(ws);                 //  4 MB  [0,4M)   dead after proj-gemm
  _Float16* wcat = (_Float16*)(ws + (4u << 20));    // 10 MB  [4,14M)  dead after proj-gemm
  _Float16* wot  = (_Float16*)(ws + (14u << 20));   //  2 MB  [14,16M) live till out-gemm
  _Float16* proj = (_Float16*)(ws + (16u << 20));   // 20 MB  [16,36M) dead after attn
  _Float16* attn = (_Float16*)(ws + (36u << 20));   //  4 MB  [36,40M)
  float* p0 = (float*)(ws);                         //  8 MB  [0,8M)   overlays dead xh/wcat
  float* p1 = (float*)(ws + (16u << 20));           //  8 MB  [16,24M) overlays dead proj

  k_prep<<<2560, 256, 0, stream>>>(x, Wqs, Wks, Wvs, Wkg, Wvg, Wo, xh, wcat, wot);
  k_gemm128b<true, true><<<dim3(16, 40, 1), 256, 0, stream>>>(
      xh, wcat, proj, nullptr, nullptr, cos_t, sin_t, pos, SEQ, PW, DMODEL, DMODEL);
  k_attn<<<dim3(79, NHEADS), 256, 0, stream>>>(proj, attn);
  k_gemm128b<false, false><<<dim3(16, 8, 2), 256, 0, stream>>>(
      attn, wot, nullptr, p0, p1, cos_t, sin_t, pos, SEQ, DMODEL, DMODEL, 512);
  k_reduce<<<SEQ * DMODEL / 1024, 256, 0, stream>>>(p0, p1, out);
}

// Round 6
// 172.027 us; speedup vs baseline: 2.8299x; 1.0684x over previous
//
#include <hip/hip_runtime.h>

typedef _Float16 half8 __attribute__((ext_vector_type(8)));
typedef float floatx4 __attribute__((ext_vector_type(4)));

#define SEQ 2048
#define DMODEL 1024
#define NHEADS 16
#define HEADDIM 64
#define PW 5120   // proj row width: q|k|v|kg|vg

// ---------------- fused prep: x fp32->fp16 + 6 weight transposes ----------------
__global__ __launch_bounds__(256) void k_prep(
    const float* __restrict__ x,
    const float* __restrict__ w0, const float* __restrict__ w1, const float* __restrict__ w2,
    const float* __restrict__ w3, const float* __restrict__ w4, const float* __restrict__ w5,
    _Float16* __restrict__ xh, _Float16* __restrict__ wcat, _Float16* __restrict__ wot) {
  const int tid = threadIdx.x;
  const int b = blockIdx.x;
  if (b < 1024) {
    int base = b * 2048 + tid * 8;
    floatx4 f0 = *(const floatx4*)(x + base);
    floatx4 f1 = *(const floatx4*)(x + base + 4);
    half8 h;
    #pragma unroll
    for (int e = 0; e < 4; ++e) { h[e] = (_Float16)f0[e]; h[e + 4] = (_Float16)f1[e]; }
    *(half8*)(xh + base) = h;
    return;
  }
  __shared__ _Float16 T[64][72];
  int t = b - 1024;
  int z = t >> 8;
  int tile = t & 255;
  int k0 = (tile >> 4) * 64, n0 = (tile & 15) * 64;
  const float* W = (z == 0) ? w0 : (z == 1) ? w1 : (z == 2) ? w2
                 : (z == 3) ? w3 : (z == 4) ? w4 : w5;
  _Float16* dst = (z < 5) ? (wcat + (size_t)z * 1024 * 1024) : wot;

  int lr = tid >> 2, c0 = (tid & 3) * 16;
  #pragma unroll
  for (int i = 0; i < 4; ++i) {
    floatx4 f = *(const floatx4*)(W + (size_t)(k0 + lr) * DMODEL + n0 + c0 + i * 4);
    #pragma unroll
    for (int e = 0; e < 4; ++e) T[c0 + i * 4 + e][lr] = (_Float16)f[e];
  }
  __syncthreads();
  int nr = tid >> 2, s0 = (tid & 3) * 16;
  #pragma unroll
  for (int i = 0; i < 2; ++i) {
    half8 h = *(const half8*)&T[nr][s0 + i * 8];
    *(half8*)(dst + (size_t)(n0 + nr) * DMODEL + k0 + s0 + i * 8) = h;
  }
}

// ---------------- 128x128 MFMA GEMM, BK=128, global_load_lds + XOR swizzle ----------------
// SPARSE (proj path): 1D grid of 400 blocks — b<384: full q|k|v (N=3072);
//   b>=384: kg|vg columns (n0 = 3072 + (b-384)*128) computed ONLY for m0=0
//   (reference uses kg/vg rows 0..3 only; rows 4.. of that region stay unwritten).
// HALF_OUT: fp16 to Cv (+ fused RoPE for n0<2048). !HALF_OUT: fp32 split-K partials.
template <bool HALF_OUT, bool FUSE_ROPE, bool SPARSE>
__global__ __launch_bounds__(256, 2) void k_gemm128b(
    const _Float16* __restrict__ A, const _Float16* __restrict__ Bt,
    void* __restrict__ Cv, float* __restrict__ Cp0, float* __restrict__ Cp1,
    const float* __restrict__ cos_t, const float* __restrict__ sin_t,
    const int* __restrict__ pos, int M, int N, int K, int kLen) {
  __shared__ _Float16 As[128][128];  // 32 KB
  __shared__ _Float16 Bs[128][128];  // 32 KB
  const int tid = threadIdx.x;
  const int lane = tid & 63;
  const int w = tid >> 6;
  const int wm = (w >> 1) * 64;
  const int wn = (w & 1) * 64;
  const int l15 = lane & 15;
  const int q4 = lane >> 4;
  int m0, n0, kStart;
  if (SPARSE) {
    int b = blockIdx.x;
    if (b < 384) { m0 = (b & 15) * 128; n0 = (b >> 4) * 128; }
    else         { m0 = 0;              n0 = 3072 + (b - 384) * 128; }
    kStart = 0;
  } else {
    m0 = blockIdx.x * 128;
    n0 = blockIdx.y * 128;
    kStart = blockIdx.z * kLen;
  }

  floatx4 acc[4][4];
  #pragma unroll
  for (int i = 0; i < 4; ++i)
    #pragma unroll
    for (int j = 0; j < 4; ++j) acc[i][j] = (floatx4){0.f, 0.f, 0.f, 0.f};

  _Float16* asBase = &As[0][0];
  _Float16* bsBase = &Bs[0][0];
  const int swz = l15 & 7;

  for (int k0 = kStart; k0 < kStart + kLen; k0 += 128) {
    __syncthreads();
    #pragma unroll
    for (int it = 0; it < 8; ++it) {
      int c = it * 256 + tid;          // chunk 0..2047 (16B each), 16 chunks/row
      int r = c >> 4, cc = c & 15;
      int g = cc ^ (r & 7);            // swizzled global k-chunk
      __builtin_amdgcn_global_load_lds(
          (const __attribute__((address_space(1))) void*)(A + (size_t)(m0 + r) * K + k0 + g * 8),
          (__attribute__((address_space(3))) void*)(asBase + (it * 256 + w * 64) * 8),
          16, 0, 0);
      __builtin_amdgcn_global_load_lds(
          (const __attribute__((address_space(1))) void*)(Bt + (size_t)(n0 + r) * K + k0 + g * 8),
          (__attribute__((address_space(3))) void*)(bsBase + (it * 256 + w * 64) * 8),
          16, 0, 0);
    }
    __syncthreads();

    #pragma unroll
    for (int kk = 0; kk < 4; ++kk) {
      int q = kk * 4 + q4;             // global k-chunk 0..15
      half8 af[4], bf[4];
      #pragma unroll
      for (int t = 0; t < 4; ++t) {
        int ar = wm + t * 16 + l15;
        af[t] = *(const half8*)(asBase + (size_t)ar * 128 + ((q ^ swz) * 8));
        int br = wn + t * 16 + l15;
        bf[t] = *(const half8*)(bsBase + (size_t)br * 128 + ((q ^ swz) * 8));
      }
      #pragma unroll
      for (int i = 0; i < 4; ++i)
        #pragma unroll
        for (int j = 0; j < 4; ++j)
          acc[i][j] = __builtin_amdgcn_mfma_f32_16x16x32_f16(af[i], bf[j], acc[i][j], 0, 0, 0);
    }
  }

  float* P = HALF_OUT ? nullptr : ((!SPARSE && blockIdx.z) ? Cp1 : Cp0);
  #pragma unroll
  for (int tm = 0; tm < 4; ++tm) {
    #pragma unroll
    for (int r = 0; r < 4; ++r) {
      int row = m0 + wm + tm * 16 + q4 * 4 + r;
      float v[4];
      #pragma unroll
      for (int tn = 0; tn < 4; ++tn) v[tn] = acc[tm][tn][r];
      if (FUSE_ROPE && n0 < 2048) {
        int p = pos[row];
        #pragma unroll
        for (int tn = 0; tn < 2; ++tn) {
          int d = tn * 16 + l15;
          float a = acc[tm][tn][r];
          float bvv = acc[tm][tn + 2][r];
          float c1 = cos_t[p * 64 + d],      s1 = sin_t[p * 64 + d];
          float c2 = cos_t[p * 64 + d + 32], s2 = sin_t[p * 64 + d + 32];
          v[tn]     = a * c1 - bvv * s1;
          v[tn + 2] = bvv * c2 + a * s2;
        }
      }
      #pragma unroll
      for (int tn = 0; tn < 4; ++tn) {
        int col = n0 + wn + tn * 16 + l15;
        if (HALF_OUT)
          ((_Float16*)Cv)[(size_t)row * N + col] = (_Float16)v[tn];
        else
          P[(size_t)row * N + col] = v[tn];
      }
    }
  }
}

// ---------------- split-K reduce: out = p0 + p1 (fp32) ----------------
__global__ __launch_bounds__(256) void k_reduce(const float* __restrict__ p0,
                                                const float* __restrict__ p1,
                                                float* __restrict__ out) {
  int i = (blockIdx.x * 256 + threadIdx.x) * 4;
  floatx4 a = *(const floatx4*)(p0 + i);
  floatx4 b = *(const floatx4*)(p1 + i);
  *(floatx4*)(out + i) = a + b;
}

// ---------------- merged attention: BM=128 flash tiles + early rows ----------------
__global__ __launch_bounds__(256, 2) void k_attn(const _Float16* __restrict__ proj,
                                                 _Float16* __restrict__ out) {
  const int tid = threadIdx.x;
  const int hb = blockIdx.y * 64;

  if (blockIdx.x >= 14) {
    // ---- early rows (absorbed-1e9: uniform average over in-window global cols) ----
    const int i = (blockIdx.x - 14) * 4 + (tid >> 6);
    const int lane = tid & 63;
    const float scale = 0.125f;
    float qv = (float)proj[(size_t)i * PW + hb + lane];
    float sg[4];
    #pragma unroll
    for (int g = 0; g < 4; ++g) {
      float kgv = (float)proj[(size_t)g * PW + 3072 + hb + lane];
      float v = qv * kgv;
      #pragma unroll
      for (int off = 32; off; off >>= 1) v += __shfl_xor(v, off, 64);
      sg[g] = v * scale;
    }
    float mg = fmaxf(fmaxf(sg[0], sg[1]), fmaxf(sg[2], sg[3]));
    float dg = 0.f, og = 0.f;
    #pragma unroll
    for (int g = 0; g < 4; ++g) {
      float p = __expf(sg[g] - mg);
      dg += p;
      og += p * (float)proj[(size_t)g * PW + 4096 + hb + lane];
    }
    og /= dg;
    int jmin = (i >= 256) ? (i - 256) : 0;
    int jmax = (i < 3) ? i : 3;
    float acc = 0.f;
    for (int j = jmin; j <= jmax; ++j)
      acc += (float)proj[(size_t)j * PW + 2048 + hb + lane];
    float ol = acc / (float)(jmax - jmin + 1);
    out[(size_t)i * DMODEL + hb + lane] = (_Float16)(ol + og);
    return;
  }

  // ---- flash path: 128 Q-rows per block, 6 chunks of 64 cols ----
  const int i0 = 256 + blockIdx.x * 128;
  const int jlo = i0 - 256;
  const int lane = tid & 63;
  const int w = tid >> 6;
  const int l15 = lane & 15;
  const int q4 = lane >> 4;

  __shared__ _Float16 Qs[128][72];
  __shared__ _Float16 Kc[64][72];
  __shared__ _Float16 Vtc[64][72];
  __shared__ _Float16 Ps[128][72];
  __shared__ _Float16 kg_s[4][64];
  __shared__ _Float16 vg_s[4][64];
  __shared__ float svg_s[64];
  __shared__ float pg_s[4][128];

  #pragma unroll
  for (int rep = 0; rep < 4; ++rep) {
    int c = tid + rep * 256;
    int r = c >> 3, q = c & 7;
    *(half8*)&Qs[r][q * 8] = *(const half8*)(proj + (size_t)(i0 + r) * PW + hb + q * 8);
  }
  {
    int g = tid >> 6, c2 = tid & 63;
    kg_s[g][c2] = proj[(size_t)g * PW + 3072 + hb + c2];
    vg_s[g][c2] = proj[(size_t)g * PW + 4096 + hb + c2];
    if (tid < 64) {
      float s = 0.f;
      #pragma unroll
      for (int g2 = 0; g2 < 4; ++g2) s += (float)proj[(size_t)g2 * PW + 2048 + hb + tid];
      svg_s[tid] = s;
    }
  }
  __syncthreads();

  #pragma unroll
  for (int pass = 0; pass < 2; ++pass) {
    int ro = pass * 64 + w * 16 + (lane >> 2);
    int part = lane & 3;
    float sg[4];
    #pragma unroll
    for (int g = 0; g < 4; ++g) {
      float acc = 0.f;
      #pragma unroll
      for (int u = 0; u < 16; ++u)
        acc += (float)Qs[ro][part * 16 + u] * (float)kg_s[g][part * 16 + u];
      acc += __shfl_xor(acc, 1, 64);
      acc += __shfl_xor(acc, 2, 64);
      sg[g] = acc * 0.125f;
    }
    float mg = fmaxf(fmaxf(sg[0], sg[1]), fmaxf(sg[2], sg[3]));
    float dg = 0.f;
    #pragma unroll
    for (int g = 0; g < 4; ++g) dg += __expf(sg[g] - mg);
    pg_s[part][ro] = __expf(sg[part] - mg) / dg;
  }

  half8 qf[2][2];
  #pragma unroll
  for (int rg = 0; rg < 2; ++rg) {
    int row = w * 32 + rg * 16 + l15;
    qf[rg][0] = *(const half8*)&Qs[row][q4 * 8];
    qf[rg][1] = *(const half8*)&Qs[row][32 + q4 * 8];
  }

  float m_r[2][4], l_r[2][4];
  floatx4 oacc[2][4];
  #pragma unroll
  for (int rg = 0; rg < 2; ++rg)
    #pragma unroll
    for (int cb = 0; cb < 4; ++cb) {
      oacc[rg][cb] = (floatx4){0.f, 0.f, 0.f, 0.f};
      m_r[rg][cb] = 0.f;
      l_r[rg][cb] = 4.f;   // 4 global cols with fp32 score exactly 0
    }

  for (int cc = 0; cc < 6; ++cc) {
    const int jbase = jlo + cc * 64;
    __syncthreads();
    #pragma unroll
    for (int rep = 0; rep < 2; ++rep) {
      int c = tid + rep * 256;
      int r = c >> 3, q = c & 7;
      *(half8*)&Kc[r][q * 8] =
          *(const half8*)(proj + (size_t)(jbase + r) * PW + 1024 + hb + q * 8);
    }
    #pragma unroll
    for (int it = 0; it < 2; ++it) {
      int idx = it * 256 + tid;
      int j = (idx & 7) + ((idx >> 6) << 3);
      int d0 = ((idx >> 3) & 7) * 8;
      half8 vv = *(const half8*)(proj + (size_t)(jbase + j) * PW + 2048 + hb + d0);
      #pragma unroll
      for (int u = 0; u < 8; ++u) Vtc[d0 + u][j] = vv[u];
    }
    __syncthreads();

    #pragma unroll
    for (int rg = 0; rg < 2; ++rg) {
      float sc[4][4];
      #pragma unroll
      for (int cb = 0; cb < 4; ++cb) {
        half8 b0 = *(const half8*)&Kc[cb * 16 + l15][q4 * 8];
        half8 b1 = *(const half8*)&Kc[cb * 16 + l15][32 + q4 * 8];
        floatx4 a = (floatx4){0.f, 0.f, 0.f, 0.f};
        a = __builtin_amdgcn_mfma_f32_16x16x32_f16(qf[rg][0], b0, a, 0, 0, 0);
        a = __builtin_amdgcn_mfma_f32_16x16x32_f16(qf[rg][1], b1, a, 0, 0, 0);
        #pragma unroll
        for (int r = 0; r < 4; ++r) sc[cb][r] = a[r];
      }

      #pragma unroll
      for (int r = 0; r < 4; ++r) {
        int ri = w * 32 + rg * 16 + q4 * 4 + r;
        float rowmax = -1e30f;
        #pragma unroll
        for (int cb = 0; cb < 4; ++cb) {
          int jjg = cc * 64 + cb * 16 + l15;
          bool valid = (jjg >= ri) && (jjg <= ri + 256);
          float s = valid ? sc[cb][r] * 0.125f : -1e30f;
          sc[cb][r] = s;
          rowmax = fmaxf(rowmax, s);
        }
        #pragma unroll
        for (int off = 1; off < 16; off <<= 1)
          rowmax = fmaxf(rowmax, __shfl_xor(rowmax, off, 64));
        float m_new = fmaxf(m_r[rg][r], rowmax);
        float alpha = __expf(m_r[rg][r] - m_new);
        float rs = 0.f;
        #pragma unroll
        for (int cb = 0; cb < 4; ++cb) {
          float p = __expf(sc[cb][r] - m_new);
          Ps[ri][cb * 16 + l15] = (_Float16)p;
          rs += p;
        }
        #pragma unroll
        for (int off = 1; off < 16; off <<= 1) rs += __shfl_xor(rs, off, 64);
        l_r[rg][r] = l_r[rg][r] * alpha + rs;
        m_r[rg][r] = m_new;
        #pragma unroll
        for (int cb = 0; cb < 4; ++cb) oacc[rg][cb][r] *= alpha;
      }

      half8 pf0 = *(const half8*)&Ps[w * 32 + rg * 16 + l15][q4 * 8];
      half8 pf1 = *(const half8*)&Ps[w * 32 + rg * 16 + l15][32 + q4 * 8];
      #pragma unroll
      for (int cb = 0; cb < 4; ++cb) {
        half8 v0 = *(const half8*)&Vtc[cb * 16 + l15][q4 * 8];
        half8 v1 = *(const half8*)&Vtc[cb * 16 + l15][32 + q4 * 8];
        oacc[rg][cb] = __builtin_amdgcn_mfma_f32_16x16x32_f16(pf0, v0, oacc[rg][cb], 0, 0, 0);
        oacc[rg][cb] = __builtin_amdgcn_mfma_f32_16x16x32_f16(pf1, v1, oacc[rg][cb], 0, 0, 0);
      }
    }
  }

  #pragma unroll
  for (int rg = 0; rg < 2; ++rg)
    #pragma unroll
    for (int r = 0; r < 4; ++r) {
      int ri = w * 32 + rg * 16 + q4 * 4 + r;
      if (i0 + ri < 260) continue;
      float e0 = __expf(-m_r[rg][r]);
      float inv = 1.f / l_r[rg][r];
      #pragma unroll
      for (int cb = 0; cb < 4; ++cb) {
        int col = cb * 16 + l15;
        float ol = (oacc[rg][cb][r] + e0 * svg_s[col]) * inv;
        float og = 0.f;
        #pragma unroll
        for (int g = 0; g < 4; ++g) og += pg_s[g][ri] * (float)vg_s[g][col];
        out[(size_t)(i0 + ri) * DMODEL + hb + col] = (_Float16)(ol + og);
      }
    }
}

// ---------------- launcher ----------------
extern "C" void kernel_launch(void* const* d_in, const int* in_sizes, int n_in,
                              void* d_out, int out_size, void* d_ws, size_t ws_size,
                              hipStream_t stream) {
  const float* x     = (const float*)d_in[0];
  const float* cos_t = (const float*)d_in[1];
  const float* sin_t = (const float*)d_in[2];
  const int*   pos   = (const int*)d_in[3];
  const float* Wqs   = (const float*)d_in[4];
  const float* Wks   = (const float*)d_in[5];
  const float* Wvs   = (const float*)d_in[6];
  const float* Wkg   = (const float*)d_in[8];
  const float* Wvg   = (const float*)d_in[9];
  const float* Wo    = (const float*)d_in[10];
  float* out = (float*)d_out;

  char* ws = (char*)d_ws;
  _Float16* xh   = (_Float16*)(ws);                 //  4 MB  dead after proj-gemm
  _Float16* wcat = (_Float16*)(ws + (4u << 20));    // 10 MB  dead after proj-gemm
  _Float16* wot  = (_Float16*)(ws + (14u << 20));   //  2 MB  live till out-gemm
  _Float16* proj = (_Float16*)(ws + (16u << 20));   // 20 MB  dead after attn
  _Float16* attn = (_Float16*)(ws + (36u << 20));   //  4 MB
  float* p0 = (float*)(ws);                         //  8 MB  overlays dead xh/wcat
  float* p1 = (float*)(ws + (16u << 20));           //  8 MB  overlays dead proj

  k_prep<<<2560, 256, 0, stream>>>(x, Wqs, Wks, Wvs, Wkg, Wvg, Wo, xh, wcat, wot);
  // sparse proj GEMM: 384 blocks q|k|v (all M) + 16 blocks kg|vg (m0=0 only)
  k_gemm128b<true, true, true><<<400, 256, 0, stream>>>(
      xh, wcat, proj, nullptr, nullptr, cos_t, sin_t, pos, SEQ, PW, DMODEL, DMODEL);
  k_attn<<<dim3(79, NHEADS), 256, 0, stream>>>(proj, attn);
  k_gemm128b<false, false, false><<<dim3(16, 8, 2), 256, 0, stream>>>(
      attn, wot, nullptr, p0, p1, cos_t, sin_t, pos, SEQ, DMODEL, DMODEL, 512);
  k_reduce<<<SEQ * DMODEL / 1024, 256, 0, stream>>>(p0, p1, out);
}